// Round 1
// baseline (6689.379 us; speedup 1.0000x reference)
//
#include <hip/hip_runtime.h>
#include <math.h>

// Problem constants (fixed by setup_inputs in the reference)
#define B_SZ   2
#define SEQ    2048
#define DM     1024
#define NH     16
#define DH     64
#define MROWS  (B_SZ * SEQ)      // 4096

// ---------------------------------------------------------------------------
// Naive fp32 tiled GEMM:  C[m][n] = sum_k A[m][k] * W[n][k]
// A: (M,K) row-major, W: (N,K) row-major, C: (M,N) row-major.
// ---------------------------------------------------------------------------
#define TILE 16
__global__ __launch_bounds__(256) void gemm_nt(const float* __restrict__ A,
                                               const float* __restrict__ W,
                                               float* __restrict__ C,
                                               int M, int N, int K) {
    __shared__ float As[TILE][TILE + 1];
    __shared__ float Ws[TILE][TILE + 1];
    const int tx = threadIdx.x, ty = threadIdx.y;
    const int row = blockIdx.y * TILE + ty;
    const int colbase = blockIdx.x * TILE;
    float acc = 0.f;
    for (int k0 = 0; k0 < K; k0 += TILE) {
        As[ty][tx] = A[(size_t)row * K + k0 + tx];
        Ws[ty][tx] = W[(size_t)(colbase + ty) * K + k0 + tx];
        __syncthreads();
#pragma unroll
        for (int kk = 0; kk < TILE; ++kk)
            acc += As[ty][kk] * Ws[tx][kk];
        __syncthreads();
    }
    C[(size_t)row * N + colbase + tx] = acc;
}

// ---------------------------------------------------------------------------
// RoPE applied in place to q and k.
// Layout: t[(b*SEQ + s)*DM + h*DH + 2i], pair (2i, 2i+1), angle = s*theta^(-2i/DH)
// idx = ((b*SEQ+s)*NH + h)*32 + i
// ---------------------------------------------------------------------------
__global__ __launch_bounds__(256) void rope_qk(float* __restrict__ q,
                                               float* __restrict__ k,
                                               int total) {
    int idx = blockIdx.x * blockDim.x + threadIdx.x;
    if (idx >= total) return;
    int i = idx & 31;
    int s = (idx >> 9) & (SEQ - 1);
    float inv = powf(10000.0f, -2.0f * (float)i / (float)DH);
    float ang = (float)s * inv;
    float c = cosf(ang), sn = sinf(ang);
    size_t off = ((size_t)(idx >> 5)) * 64 + 2 * i;
    float qe = q[off], qo = q[off + 1];
    q[off]     = qe * c - qo * sn;
    q[off + 1] = qe * sn + qo * c;
    float ke = k[off], ko = k[off + 1];
    k[off]     = ke * c - ko * sn;
    k[off + 1] = ke * sn + ko * c;
}

// ---------------------------------------------------------------------------
// Causal attention, flash-style online softmax.
// One wave (64 lanes) per query row; lane d owns head-dim d.
// q,k,v layout: [(b*SEQ + s)*DM + h*DH + d]
// ---------------------------------------------------------------------------
__global__ __launch_bounds__(64) void attn_fwd(const float* __restrict__ q,
                                               const float* __restrict__ k,
                                               const float* __restrict__ v,
                                               float* __restrict__ o) {
    const int row = blockIdx.x;
    const int bh  = blockIdx.y;           // b*NH + h
    const int b   = bh >> 4;
    const int h   = bh & (NH - 1);
    const int lane = threadIdx.x;
    const float scale = 0.125f;           // 1/sqrt(64)

    const size_t qoff = ((size_t)(b * SEQ + row)) * DM + h * DH;
    const float qd = q[qoff + lane] * scale;
    const float* kb = k + (size_t)b * SEQ * DM + h * DH;
    const float* vb = v + (size_t)b * SEQ * DM + h * DH;

    float m = -INFINITY, l = 0.f, acc = 0.f;
    for (int kk = 0; kk <= row; ++kk) {
        float x = qd * kb[(size_t)kk * DM + lane];
#pragma unroll
        for (int off = 32; off; off >>= 1)
            x += __shfl_xor(x, off);
        float mn = fmaxf(m, x);
        float p  = __expf(x - mn);
        float f  = __expf(m - mn);
        l   = l * f + p;
        acc = acc * f + p * vb[(size_t)kk * DM + lane];
        m = mn;
    }
    o[qoff + lane] = acc / l;
}

// ---------------------------------------------------------------------------
extern "C" void kernel_launch(void* const* d_in, const int* in_sizes, int n_in,
                              void* d_out, int out_size, void* d_ws, size_t ws_size,
                              hipStream_t stream) {
    const float* x  = (const float*)d_in[0];
    const float* wq = (const float*)d_in[1];
    const float* wk = (const float*)d_in[2];
    const float* wv = (const float*)d_in[3];
    const float* wo = (const float*)d_in[4];
    float* out = (float*)d_out;

    const size_t TSZ = (size_t)MROWS * DM;   // 4 M elements
    float* q    = (float*)d_ws;
    float* kbuf = q + TSZ;
    float* vbuf = kbuf + TSZ;
    float* attn = vbuf + TSZ;

    dim3 blk(TILE, TILE);
    dim3 grd(DM / TILE, MROWS / TILE);
    gemm_nt<<<grd, blk, 0, stream>>>(x, wq, q,    MROWS, DM, DM);
    gemm_nt<<<grd, blk, 0, stream>>>(x, wk, kbuf, MROWS, DM, DM);
    gemm_nt<<<grd, blk, 0, stream>>>(x, wv, vbuf, MROWS, DM, DM);

    int total = MROWS * NH * 32;             // pairs per tensor
    rope_qk<<<(total + 255) / 256, 256, 0, stream>>>(q, kbuf, total);

    attn_fwd<<<dim3(SEQ, B_SZ * NH), 64, 0, stream>>>(q, kbuf, vbuf, attn);

    gemm_nt<<<grd, blk, 0, stream>>>(attn, wo, out, MROWS, DM, DM);
}

// Round 2
// 2326.268 us; speedup vs baseline: 2.8756x; 2.8756x over previous
//
#include <hip/hip_runtime.h>
#include <math.h>

// Problem constants
#define B_SZ   2
#define SEQ    2048
#define DM     1024
#define NH     16
#define DH     64
#define MROWS  (B_SZ * SEQ)      // 4096

typedef __attribute__((ext_vector_type(8))) short short8;
typedef __attribute__((ext_vector_type(4))) float f32x4;
typedef __attribute__((ext_vector_type(4))) unsigned short us4;

// bf16 <-> f32 helpers (ushort storage, RNE rounding)
__device__ __forceinline__ float b2f(unsigned short u) {
    union { float f; unsigned int i; } x; x.i = ((unsigned int)u) << 16; return x.f;
}
__device__ __forceinline__ unsigned short f2b(float f) {
    union { float f; unsigned int i; } x; x.f = f;
    return (unsigned short)((x.i + 0x7fffu + ((x.i >> 16) & 1u)) >> 16);
}

// ---------------------------------------------------------------------------
// fp32 tiled GEMM, fp32 out:  C = A(M,K) * W(N,K)^T
// ---------------------------------------------------------------------------
#define TILE 16
__global__ __launch_bounds__(256) void gemm_nt(const float* __restrict__ A,
                                               const float* __restrict__ W,
                                               float* __restrict__ C,
                                               int M, int N, int K) {
    __shared__ float As[TILE][TILE + 1];
    __shared__ float Ws[TILE][TILE + 1];
    const int tx = threadIdx.x, ty = threadIdx.y;
    const int row = blockIdx.y * TILE + ty;
    const int colbase = blockIdx.x * TILE;
    float acc = 0.f;
    for (int k0 = 0; k0 < K; k0 += TILE) {
        As[ty][tx] = A[(size_t)row * K + k0 + tx];
        Ws[ty][tx] = W[(size_t)(colbase + ty) * K + k0 + tx];
        __syncthreads();
#pragma unroll
        for (int kk = 0; kk < TILE; ++kk)
            acc += As[ty][kk] * Ws[tx][kk];
        __syncthreads();
    }
    C[(size_t)row * N + colbase + tx] = acc;
}

// Same GEMM but bf16 output
__global__ __launch_bounds__(256) void gemm_nt_bf16(const float* __restrict__ A,
                                                    const float* __restrict__ W,
                                                    unsigned short* __restrict__ C,
                                                    int M, int N, int K) {
    __shared__ float As[TILE][TILE + 1];
    __shared__ float Ws[TILE][TILE + 1];
    const int tx = threadIdx.x, ty = threadIdx.y;
    const int row = blockIdx.y * TILE + ty;
    const int colbase = blockIdx.x * TILE;
    float acc = 0.f;
    for (int k0 = 0; k0 < K; k0 += TILE) {
        As[ty][tx] = A[(size_t)row * K + k0 + tx];
        Ws[ty][tx] = W[(size_t)(colbase + ty) * K + k0 + tx];
        __syncthreads();
#pragma unroll
        for (int kk = 0; kk < TILE; ++kk)
            acc += As[ty][kk] * Ws[tx][kk];
        __syncthreads();
    }
    C[(size_t)row * N + colbase + tx] = f2b(acc);
}

// ---------------------------------------------------------------------------
// RoPE in place on bf16 q,k. q additionally scaled by 1/sqrt(DH).
// ---------------------------------------------------------------------------
__global__ __launch_bounds__(256) void rope_qk_bf16(unsigned short* __restrict__ q,
                                                    unsigned short* __restrict__ k,
                                                    int total) {
    int idx = blockIdx.x * blockDim.x + threadIdx.x;
    if (idx >= total) return;
    int i = idx & 31;
    int s = (idx >> 9) & (SEQ - 1);
    float inv = powf(10000.0f, -2.0f * (float)i / (float)DH);
    float ang = (float)s * inv;
    float c = cosf(ang), sn = sinf(ang);
    size_t off = ((size_t)(idx >> 5)) * 64 + 2 * i;
    const float scale = 0.125f;
    float qe = b2f(q[off]), qo = b2f(q[off + 1]);
    q[off]     = f2b((qe * c - qo * sn) * scale);
    q[off + 1] = f2b((qe * sn + qo * c) * scale);
    float ke = b2f(k[off]), ko = b2f(k[off + 1]);
    k[off]     = f2b(ke * c - ko * sn);
    k[off + 1] = f2b(ke * sn + ko * c);
}

// ---------------------------------------------------------------------------
// Transpose V: [b, s, h, d]  ->  vT[(b*NH+h)*DH + d][s]   (bf16)
// ---------------------------------------------------------------------------
__global__ __launch_bounds__(256) void transpose_v(const unsigned short* __restrict__ v,
                                                   unsigned short* __restrict__ vT) {
    __shared__ unsigned short t[64][68];
    const int s0 = blockIdx.x * 64;
    const int bh = blockIdx.y;
    const int b = bh >> 4, h = bh & 15;
    const int tid = threadIdx.x;
    for (int idx = tid; idx < 1024; idx += 256) {
        int s = idx >> 4;
        int dg = (idx & 15) * 4;
        us4 val = *reinterpret_cast<const us4*>(v + (size_t)(b * SEQ + s0 + s) * DM + h * DH + dg);
        *reinterpret_cast<us4*>(&t[s][dg]) = val;
    }
    __syncthreads();
    for (int idx = tid; idx < 1024; idx += 256) {
        int d = idx >> 4;
        int sg = (idx & 15) * 4;
        us4 val;
        val.x = t[sg + 0][d];
        val.y = t[sg + 1][d];
        val.z = t[sg + 2][d];
        val.w = t[sg + 3][d];
        *reinterpret_cast<us4*>(vT + (size_t)(bh * DH + d) * SEQ + s0 + sg) = val;
    }
}

// ---------------------------------------------------------------------------
// MFMA flash attention. 1 wave per 16-query tile per (b,h).
// q,k: bf16 [(b*SEQ+s)*DM + h*DH + d]  (q pre-scaled)
// vT:  bf16 [(b*NH+h)*DH + d][s]
// o:   fp32 [(b*SEQ+s)*DM + h*DH + d]
// MFMA 16x16x32 layouts: A row=lane%16, k=(lane/16)*8+i ; B col=lane%16, same k;
// D col=lane&15, row=(lane>>4)*4+reg.
// ---------------------------------------------------------------------------
__global__ __launch_bounds__(64) void attn_mfma(const unsigned short* __restrict__ qbf,
                                                const unsigned short* __restrict__ kbf,
                                                const unsigned short* __restrict__ vT,
                                                float* __restrict__ o) {
    const int qi = blockIdx.x;            // 0..127
    const int bh = blockIdx.y;            // b*NH+h
    const int b = bh >> 4, h = bh & 15;
    const int lane = threadIdx.x;
    const int lm = lane & 15, lg = lane >> 4;
    const int qbase = qi * 16;

    __shared__ unsigned short Pl[16][40];  // padded P tile

    const unsigned short* qrow = qbf + ((size_t)(b * SEQ + qbase + lm)) * DM + h * DH;
    short8 qa0 = *reinterpret_cast<const short8*>(qrow + lg * 8);
    short8 qa1 = *reinterpret_cast<const short8*>(qrow + 32 + lg * 8);

    const unsigned short* kb = kbf + ((size_t)b * SEQ) * DM + h * DH;
    const unsigned short* vb = vT + ((size_t)bh) * DH * SEQ;

    f32x4 o0 = {0.f, 0.f, 0.f, 0.f}, o1 = o0, o2 = o0, o3 = o0;
    float m[4] = {-INFINITY, -INFINITY, -INFINITY, -INFINITY};
    float l[4] = {0.f, 0.f, 0.f, 0.f};

    const int nb = (qbase + 16 + 31) >> 5;       // 32-key blocks
    for (int blk = 0; blk < nb; ++blk) {
        const int kbase = blk << 5;
        const unsigned short* kr0 = kb + (size_t)(kbase + lm) * DM;
        const unsigned short* kr1 = kb + (size_t)(kbase + 16 + lm) * DM;
        short8 k00 = *reinterpret_cast<const short8*>(kr0 + lg * 8);
        short8 k01 = *reinterpret_cast<const short8*>(kr0 + 32 + lg * 8);
        short8 k10 = *reinterpret_cast<const short8*>(kr1 + lg * 8);
        short8 k11 = *reinterpret_cast<const short8*>(kr1 + 32 + lg * 8);

        f32x4 s0 = {0.f, 0.f, 0.f, 0.f}, s1 = s0;
        s0 = __builtin_amdgcn_mfma_f32_16x16x32_bf16(qa0, k00, s0, 0, 0, 0);
        s0 = __builtin_amdgcn_mfma_f32_16x16x32_bf16(qa1, k01, s0, 0, 0, 0);
        s1 = __builtin_amdgcn_mfma_f32_16x16x32_bf16(qa0, k10, s1, 0, 0, 0);
        s1 = __builtin_amdgcn_mfma_f32_16x16x32_bf16(qa1, k11, s1, 0, 0, 0);

        if (blk == nb - 1) {
#pragma unroll
            for (int r = 0; r < 4; ++r) {
                int qg = qbase + lg * 4 + r;
                s0[r] = (kbase + lm <= qg) ? s0[r] : -INFINITY;
                s1[r] = (kbase + 16 + lm <= qg) ? s1[r] : -INFINITY;
            }
        }

        float f[4];
#pragma unroll
        for (int r = 0; r < 4; ++r) {
            float mx = fmaxf(s0[r], s1[r]);
#pragma unroll
            for (int off = 1; off < 16; off <<= 1)
                mx = fmaxf(mx, __shfl_xor(mx, off));
            float mn = fmaxf(m[r], mx);
            f[r] = __expf(m[r] - mn);
            m[r] = mn;
            float p0 = __expf(s0[r] - mn);
            float p1 = __expf(s1[r] - mn);
            s0[r] = p0; s1[r] = p1;
            float ps = p0 + p1;
#pragma unroll
            for (int off = 1; off < 16; off <<= 1)
                ps += __shfl_xor(ps, off);
            l[r] = l[r] * f[r] + ps;
        }
#pragma unroll
        for (int r = 0; r < 4; ++r) {
            o0[r] *= f[r]; o1[r] *= f[r]; o2[r] *= f[r]; o3[r] *= f[r];
        }

        // stage P (bf16) to LDS
#pragma unroll
        for (int r = 0; r < 4; ++r) {
            Pl[lg * 4 + r][lm]      = f2b(s0[r]);
            Pl[lg * 4 + r][16 + lm] = f2b(s1[r]);
        }
        __syncthreads();
        short8 pa = *reinterpret_cast<const short8*>(&Pl[lm][lg * 8]);
        __syncthreads();

        // PV: 4 output 16-col chunks
        short8 v0 = *reinterpret_cast<const short8*>(vb + (size_t)(0 * 16 + lm) * SEQ + kbase + lg * 8);
        short8 v1 = *reinterpret_cast<const short8*>(vb + (size_t)(1 * 16 + lm) * SEQ + kbase + lg * 8);
        short8 v2 = *reinterpret_cast<const short8*>(vb + (size_t)(2 * 16 + lm) * SEQ + kbase + lg * 8);
        short8 v3 = *reinterpret_cast<const short8*>(vb + (size_t)(3 * 16 + lm) * SEQ + kbase + lg * 8);
        o0 = __builtin_amdgcn_mfma_f32_16x16x32_bf16(pa, v0, o0, 0, 0, 0);
        o1 = __builtin_amdgcn_mfma_f32_16x16x32_bf16(pa, v1, o1, 0, 0, 0);
        o2 = __builtin_amdgcn_mfma_f32_16x16x32_bf16(pa, v2, o2, 0, 0, 0);
        o3 = __builtin_amdgcn_mfma_f32_16x16x32_bf16(pa, v3, o3, 0, 0, 0);
    }

    // epilogue: normalize and store fp32
#pragma unroll
    for (int r = 0; r < 4; ++r) {
        const size_t rowoff = ((size_t)(b * SEQ + qbase + lg * 4 + r)) * DM + h * DH;
        const float inv_l = 1.0f / l[r];
        o[rowoff + 0 * 16 + lm] = o0[r] * inv_l;
        o[rowoff + 1 * 16 + lm] = o1[r] * inv_l;
        o[rowoff + 2 * 16 + lm] = o2[r] * inv_l;
        o[rowoff + 3 * 16 + lm] = o3[r] * inv_l;
    }
}

// ---------------------------------------------------------------------------
extern "C" void kernel_launch(void* const* d_in, const int* in_sizes, int n_in,
                              void* d_out, int out_size, void* d_ws, size_t ws_size,
                              hipStream_t stream) {
    const float* x  = (const float*)d_in[0];
    const float* wq = (const float*)d_in[1];
    const float* wk = (const float*)d_in[2];
    const float* wv = (const float*)d_in[3];
    const float* wo = (const float*)d_in[4];
    float* out = (float*)d_out;

    const size_t TSZ = (size_t)MROWS * DM;            // 4M elements
    char* ws = (char*)d_ws;
    unsigned short* qbf  = (unsigned short*)(ws);                    // 8 MB
    unsigned short* kbf  = (unsigned short*)(ws + 8u  * 1024 * 1024);
    unsigned short* vtmp = (unsigned short*)(ws + 16u * 1024 * 1024);
    unsigned short* vT   = (unsigned short*)(ws + 24u * 1024 * 1024);
    float*          attn = (float*)        (ws + 32u * 1024 * 1024); // 16 MB

    dim3 blk(TILE, TILE);
    dim3 grd(DM / TILE, MROWS / TILE);
    gemm_nt_bf16<<<grd, blk, 0, stream>>>(x, wq, qbf,  MROWS, DM, DM);
    gemm_nt_bf16<<<grd, blk, 0, stream>>>(x, wk, kbf,  MROWS, DM, DM);
    gemm_nt_bf16<<<grd, blk, 0, stream>>>(x, wv, vtmp, MROWS, DM, DM);

    int total = MROWS * NH * 32;
    rope_qk_bf16<<<(total + 255) / 256, 256, 0, stream>>>(qbf, kbf, total);

    transpose_v<<<dim3(SEQ / 64, B_SZ * NH), 256, 0, stream>>>(vtmp, vT);

    attn_mfma<<<dim3(SEQ / 16, B_SZ * NH), 64, 0, stream>>>(qbf, kbf, vT, attn);

    gemm_nt<<<grd, blk, 0, stream>>>(attn, wo, out, MROWS, DM, DM);
}

// Round 3
// 382.908 us; speedup vs baseline: 17.4700x; 6.0753x over previous
//
#include <hip/hip_runtime.h>
#include <math.h>

// Problem constants
#define B_SZ   2
#define SEQ    2048
#define DM     1024
#define NH     16
#define DH     64
#define MROWS  (B_SZ * SEQ)      // 4096

typedef __attribute__((ext_vector_type(8))) short short8;
typedef __attribute__((ext_vector_type(4))) float f32x4;
typedef __attribute__((ext_vector_type(4))) unsigned short us4;

__device__ __forceinline__ float b2f(unsigned short u) {
    union { float f; unsigned int i; } x; x.i = ((unsigned int)u) << 16; return x.f;
}
__device__ __forceinline__ unsigned short f2b(float f) {
    union { float f; unsigned int i; } x; x.f = f;
    return (unsigned short)((x.i + 0x7fffu + ((x.i >> 16) & 1u)) >> 16);
}

// async global->LDS, 16B per lane; lds base must be wave-uniform (HW adds lane*16)
__device__ __forceinline__ void gload_lds16(const unsigned short* g, unsigned short* lds_base_uniform) {
    __builtin_amdgcn_global_load_lds(
        (const __attribute__((address_space(1))) unsigned int*)g,
        (__attribute__((address_space(3))) unsigned int*)lds_base_uniform,
        16, 0, 0);
}

// ---------------------------------------------------------------------------
// f32 -> bf16 conversion (vectorized, n % 4 == 0)
// ---------------------------------------------------------------------------
__global__ __launch_bounds__(256) void cvt_f32_bf16(const float* __restrict__ in,
                                                    unsigned short* __restrict__ out, int n) {
    int i = blockIdx.x * blockDim.x + threadIdx.x;
    if (i * 4 >= n) return;
    float4 v = reinterpret_cast<const float4*>(in)[i];
    us4 o = { f2b(v.x), f2b(v.y), f2b(v.z), f2b(v.w) };
    reinterpret_cast<us4*>(out)[i] = o;
}

// ---------------------------------------------------------------------------
// bf16 MFMA GEMM (m97 structure, single-buffered):
// C[m][n] = sum_k A[m][k]*B[n][k], A (M,K) bf16 row-major, B (N,K) bf16 row-major.
// 128x128 tile, BK=32, 4 waves (2x2), each wave 64x64 = 4x4 MFMA fragments.
// ---------------------------------------------------------------------------
#define BM 128
#define BN 128
#define BK 32

template <bool BF16OUT>
__global__ __launch_bounds__(256) void gemm_bt_mfma(const unsigned short* __restrict__ A,
                                                    const unsigned short* __restrict__ B,
                                                    void* __restrict__ Cout,
                                                    int M, int N, int K) {
    __shared__ unsigned short As[BM * BK];   // 8 KB
    __shared__ unsigned short Bs[BN * BK];   // 8 KB
    const int tid  = threadIdx.x;
    const int lane = tid & 63, wid = tid >> 6;
    const int wr = wid >> 1, wc = wid & 1;
    const int lm = lane & 15, lg = lane >> 4;
    const int brow = blockIdx.y * BM, bcol = blockIdx.x * BN;

    f32x4 acc[4][4] = {};

    // staging: thread t covers 16B chunks t and t+256 of the 8KB tile
    const int rA  = tid >> 2;          // row 0..63 (first chunk)
    const int kc8 = (tid & 3) * 8;     // k element offset
    const unsigned short* gA0 = A + (size_t)(brow + rA) * K + kc8;
    const unsigned short* gA1 = A + (size_t)(brow + 64 + rA) * K + kc8;
    const unsigned short* gB0 = B + (size_t)(bcol + rA) * K + kc8;
    const unsigned short* gB1 = B + (size_t)(bcol + 64 + rA) * K + kc8;
    unsigned short* lA0 = As + wid * 512;          // bytes: wid*1024
    unsigned short* lA1 = As + 2048 + wid * 512;   // second 4KB half
    unsigned short* lB0 = Bs + wid * 512;
    unsigned short* lB1 = Bs + 2048 + wid * 512;

    for (int k0 = 0; k0 < K; k0 += BK) {
        gload_lds16(gA0 + k0, lA0);
        gload_lds16(gA1 + k0, lA1);
        gload_lds16(gB0 + k0, lB0);
        gload_lds16(gB1 + k0, lB1);
        __syncthreads();

        short8 a[4], b[4];
#pragma unroll
        for (int m = 0; m < 4; ++m)
            a[m] = *reinterpret_cast<const short8*>(&As[(wr * 64 + m * 16 + lm) * BK + lg * 8]);
#pragma unroll
        for (int n = 0; n < 4; ++n)
            b[n] = *reinterpret_cast<const short8*>(&Bs[(wc * 64 + n * 16 + lm) * BK + lg * 8]);
#pragma unroll
        for (int m = 0; m < 4; ++m)
#pragma unroll
            for (int n = 0; n < 4; ++n)
                acc[m][n] = __builtin_amdgcn_mfma_f32_16x16x32_bf16(a[m], b[n], acc[m][n], 0, 0, 0);
        __syncthreads();
    }

    // epilogue: C/D layout col=lane&15, row=(lane>>4)*4+reg
#pragma unroll
    for (int m = 0; m < 4; ++m) {
#pragma unroll
        for (int r = 0; r < 4; ++r) {
            const size_t base = (size_t)(brow + wr * 64 + m * 16 + lg * 4 + r) * N + bcol + wc * 64 + lm;
#pragma unroll
            for (int n = 0; n < 4; ++n) {
                if (BF16OUT)
                    ((unsigned short*)Cout)[base + n * 16] = f2b(acc[m][n][r]);
                else
                    ((float*)Cout)[base + n * 16] = acc[m][n][r];
            }
        }
    }
}

// ---------------------------------------------------------------------------
// RoPE in place on bf16 q,k. q additionally scaled by 1/sqrt(DH).
// ---------------------------------------------------------------------------
__global__ __launch_bounds__(256) void rope_qk_bf16(unsigned short* __restrict__ q,
                                                    unsigned short* __restrict__ k,
                                                    int total) {
    int idx = blockIdx.x * blockDim.x + threadIdx.x;
    if (idx >= total) return;
    int i = idx & 31;
    int s = (idx >> 9) & (SEQ - 1);
    float inv = powf(10000.0f, -2.0f * (float)i / (float)DH);
    float ang = (float)s * inv;
    float c = cosf(ang), sn = sinf(ang);
    size_t off = ((size_t)(idx >> 5)) * 64 + 2 * i;
    const float scale = 0.125f;
    float qe = b2f(q[off]), qo = b2f(q[off + 1]);
    q[off]     = f2b((qe * c - qo * sn) * scale);
    q[off + 1] = f2b((qe * sn + qo * c) * scale);
    float ke = b2f(k[off]), ko = b2f(k[off + 1]);
    k[off]     = f2b(ke * c - ko * sn);
    k[off + 1] = f2b(ke * sn + ko * c);
}

// ---------------------------------------------------------------------------
// Transpose V: [b, s, h, d] -> vT[(b*NH+h)*DH + d][s]   (bf16)
// ---------------------------------------------------------------------------
__global__ __launch_bounds__(256) void transpose_v(const unsigned short* __restrict__ v,
                                                   unsigned short* __restrict__ vT) {
    __shared__ unsigned short t[64][68];
    const int s0 = blockIdx.x * 64;
    const int bh = blockIdx.y;
    const int b = bh >> 4, h = bh & 15;
    const int tid = threadIdx.x;
    for (int idx = tid; idx < 1024; idx += 256) {
        int s = idx >> 4;
        int dg = (idx & 15) * 4;
        us4 val = *reinterpret_cast<const us4*>(v + (size_t)(b * SEQ + s0 + s) * DM + h * DH + dg);
        *reinterpret_cast<us4*>(&t[s][dg]) = val;
    }
    __syncthreads();
    for (int idx = tid; idx < 1024; idx += 256) {
        int d = idx >> 4;
        int sg = (idx & 15) * 4;
        us4 val;
        val.x = t[sg + 0][d];
        val.y = t[sg + 1][d];
        val.z = t[sg + 2][d];
        val.w = t[sg + 3][d];
        *reinterpret_cast<us4*>(vT + (size_t)(bh * DH + d) * SEQ + s0 + sg) = val;
    }
}

// ---------------------------------------------------------------------------
// MFMA flash attention. 1 wave per 16-query tile per (b,h). bf16 output.
// ---------------------------------------------------------------------------
__global__ __launch_bounds__(64) void attn_mfma(const unsigned short* __restrict__ qbf,
                                                const unsigned short* __restrict__ kbf,
                                                const unsigned short* __restrict__ vT,
                                                unsigned short* __restrict__ o) {
    const int qi = blockIdx.x;
    const int bh = blockIdx.y;
    const int b = bh >> 4, h = bh & 15;
    const int lane = threadIdx.x;
    const int lm = lane & 15, lg = lane >> 4;
    const int qbase = qi * 16;

    __shared__ unsigned short Pl[16][40];

    const unsigned short* qrow = qbf + ((size_t)(b * SEQ + qbase + lm)) * DM + h * DH;
    short8 qa0 = *reinterpret_cast<const short8*>(qrow + lg * 8);
    short8 qa1 = *reinterpret_cast<const short8*>(qrow + 32 + lg * 8);

    const unsigned short* kb = kbf + ((size_t)b * SEQ) * DM + h * DH;
    const unsigned short* vb = vT + ((size_t)bh) * DH * SEQ;

    f32x4 o0 = {0.f, 0.f, 0.f, 0.f}, o1 = o0, o2 = o0, o3 = o0;
    float m[4] = {-INFINITY, -INFINITY, -INFINITY, -INFINITY};
    float l[4] = {0.f, 0.f, 0.f, 0.f};

    const int nb = (qbase + 16 + 31) >> 5;
    for (int blk = 0; blk < nb; ++blk) {
        const int kbase = blk << 5;
        const unsigned short* kr0 = kb + (size_t)(kbase + lm) * DM;
        const unsigned short* kr1 = kb + (size_t)(kbase + 16 + lm) * DM;
        short8 k00 = *reinterpret_cast<const short8*>(kr0 + lg * 8);
        short8 k01 = *reinterpret_cast<const short8*>(kr0 + 32 + lg * 8);
        short8 k10 = *reinterpret_cast<const short8*>(kr1 + lg * 8);
        short8 k11 = *reinterpret_cast<const short8*>(kr1 + 32 + lg * 8);

        f32x4 s0 = {0.f, 0.f, 0.f, 0.f}, s1 = s0;
        s0 = __builtin_amdgcn_mfma_f32_16x16x32_bf16(qa0, k00, s0, 0, 0, 0);
        s0 = __builtin_amdgcn_mfma_f32_16x16x32_bf16(qa1, k01, s0, 0, 0, 0);
        s1 = __builtin_amdgcn_mfma_f32_16x16x32_bf16(qa0, k10, s1, 0, 0, 0);
        s1 = __builtin_amdgcn_mfma_f32_16x16x32_bf16(qa1, k11, s1, 0, 0, 0);

        if (blk == nb - 1) {
#pragma unroll
            for (int r = 0; r < 4; ++r) {
                int qg = qbase + lg * 4 + r;
                s0[r] = (kbase + lm <= qg) ? s0[r] : -INFINITY;
                s1[r] = (kbase + 16 + lm <= qg) ? s1[r] : -INFINITY;
            }
        }

        float f[4];
#pragma unroll
        for (int r = 0; r < 4; ++r) {
            float mx = fmaxf(s0[r], s1[r]);
#pragma unroll
            for (int off = 1; off < 16; off <<= 1)
                mx = fmaxf(mx, __shfl_xor(mx, off));
            float mn = fmaxf(m[r], mx);
            f[r] = __expf(m[r] - mn);
            m[r] = mn;
            float p0 = __expf(s0[r] - mn);
            float p1 = __expf(s1[r] - mn);
            s0[r] = p0; s1[r] = p1;
            float ps = p0 + p1;
#pragma unroll
            for (int off = 1; off < 16; off <<= 1)
                ps += __shfl_xor(ps, off);
            l[r] = l[r] * f[r] + ps;
        }
#pragma unroll
        for (int r = 0; r < 4; ++r) {
            o0[r] *= f[r]; o1[r] *= f[r]; o2[r] *= f[r]; o3[r] *= f[r];
        }

#pragma unroll
        for (int r = 0; r < 4; ++r) {
            Pl[lg * 4 + r][lm]      = f2b(s0[r]);
            Pl[lg * 4 + r][16 + lm] = f2b(s1[r]);
        }
        __syncthreads();
        short8 pa = *reinterpret_cast<const short8*>(&Pl[lm][lg * 8]);
        __syncthreads();

        short8 v0 = *reinterpret_cast<const short8*>(vb + (size_t)(0 * 16 + lm) * SEQ + kbase + lg * 8);
        short8 v1 = *reinterpret_cast<const short8*>(vb + (size_t)(1 * 16 + lm) * SEQ + kbase + lg * 8);
        short8 v2 = *reinterpret_cast<const short8*>(vb + (size_t)(2 * 16 + lm) * SEQ + kbase + lg * 8);
        short8 v3 = *reinterpret_cast<const short8*>(vb + (size_t)(3 * 16 + lm) * SEQ + kbase + lg * 8);
        o0 = __builtin_amdgcn_mfma_f32_16x16x32_bf16(pa, v0, o0, 0, 0, 0);
        o1 = __builtin_amdgcn_mfma_f32_16x16x32_bf16(pa, v1, o1, 0, 0, 0);
        o2 = __builtin_amdgcn_mfma_f32_16x16x32_bf16(pa, v2, o2, 0, 0, 0);
        o3 = __builtin_amdgcn_mfma_f32_16x16x32_bf16(pa, v3, o3, 0, 0, 0);
    }

#pragma unroll
    for (int r = 0; r < 4; ++r) {
        const size_t rowoff = ((size_t)(b * SEQ + qbase + lg * 4 + r)) * DM + h * DH;
        const float inv_l = 1.0f / l[r];
        o[rowoff + 0 * 16 + lm] = f2b(o0[r] * inv_l);
        o[rowoff + 1 * 16 + lm] = f2b(o1[r] * inv_l);
        o[rowoff + 2 * 16 + lm] = f2b(o2[r] * inv_l);
        o[rowoff + 3 * 16 + lm] = f2b(o3[r] * inv_l);
    }
}

// ---------------------------------------------------------------------------
extern "C" void kernel_launch(void* const* d_in, const int* in_sizes, int n_in,
                              void* d_out, int out_size, void* d_ws, size_t ws_size,
                              hipStream_t stream) {
    const float* x  = (const float*)d_in[0];
    const float* wq = (const float*)d_in[1];
    const float* wk = (const float*)d_in[2];
    const float* wv = (const float*)d_in[3];
    const float* wo = (const float*)d_in[4];
    float* out = (float*)d_out;

    const int TSZ = MROWS * DM;      // 4M
    const int WSZ = DM * DM;         // 1M
    char* ws = (char*)d_ws;
    const size_t MB = 1024 * 1024;
    unsigned short* xb      = (unsigned short*)(ws);             // 8 MB
    unsigned short* wqb     = (unsigned short*)(ws + 8 * MB);    // 2 MB
    unsigned short* wkb     = (unsigned short*)(ws + 10 * MB);
    unsigned short* wvb     = (unsigned short*)(ws + 12 * MB);
    unsigned short* wob     = (unsigned short*)(ws + 14 * MB);
    unsigned short* qbf     = (unsigned short*)(ws + 16 * MB);   // 8 MB
    unsigned short* kbf     = (unsigned short*)(ws + 24 * MB);   // 8 MB
    unsigned short* vtmp    = (unsigned short*)(ws + 32 * MB);   // 8 MB
    unsigned short* vT      = (unsigned short*)(ws + 40 * MB);   // 8 MB
    unsigned short* attn_bf = (unsigned short*)(ws + 32 * MB);   // reuse vtmp after transpose

    cvt_f32_bf16<<<TSZ / 4 / 256, 256, 0, stream>>>(x, xb, TSZ);
    cvt_f32_bf16<<<WSZ / 4 / 256, 256, 0, stream>>>(wq, wqb, WSZ);
    cvt_f32_bf16<<<WSZ / 4 / 256, 256, 0, stream>>>(wk, wkb, WSZ);
    cvt_f32_bf16<<<WSZ / 4 / 256, 256, 0, stream>>>(wv, wvb, WSZ);
    cvt_f32_bf16<<<WSZ / 4 / 256, 256, 0, stream>>>(wo, wob, WSZ);

    dim3 grd(DM / BN, MROWS / BM);   // (8, 32)
    gemm_bt_mfma<true><<<grd, 256, 0, stream>>>(xb, wqb, qbf,  MROWS, DM, DM);
    gemm_bt_mfma<true><<<grd, 256, 0, stream>>>(xb, wkb, kbf,  MROWS, DM, DM);
    gemm_bt_mfma<true><<<grd, 256, 0, stream>>>(xb, wvb, vtmp, MROWS, DM, DM);

    int total = MROWS * NH * 32;
    rope_qk_bf16<<<(total + 255) / 256, 256, 0, stream>>>(qbf, kbf, total);

    transpose_v<<<dim3(SEQ / 64, B_SZ * NH), 256, 0, stream>>>(vtmp, vT);

    attn_mfma<<<dim3(SEQ / 16, B_SZ * NH), 64, 0, stream>>>(qbf, kbf, vT, attn_bf);

    gemm_bt_mfma<false><<<grd, 256, 0, stream>>>(attn_bf, wob, out, MROWS, DM, DM);
}

// Round 4
// 377.910 us; speedup vs baseline: 17.7010x; 1.0132x over previous
//
#include <hip/hip_runtime.h>
#include <math.h>

// Problem constants
#define B_SZ   2
#define SEQ    2048
#define DM     1024
#define NH     16
#define DH     64
#define MROWS  (B_SZ * SEQ)      // 4096

typedef __attribute__((ext_vector_type(8))) short short8;
typedef __attribute__((ext_vector_type(4))) float f32x4;
typedef __attribute__((ext_vector_type(4))) unsigned short us4;

__device__ __forceinline__ float b2f(unsigned short u) {
    union { float f; unsigned int i; } x; x.i = ((unsigned int)u) << 16; return x.f;
}
__device__ __forceinline__ unsigned short f2b(float f) {
    union { float f; unsigned int i; } x; x.f = f;
    return (unsigned short)((x.i + 0x7fffu + ((x.i >> 16) & 1u)) >> 16);
}

// async global->LDS, 16B per lane; lds base must be wave-uniform (HW adds lane*16)
__device__ __forceinline__ void gload_lds16(const unsigned short* g, unsigned short* lds_base_uniform) {
    __builtin_amdgcn_global_load_lds(
        (const __attribute__((address_space(1))) unsigned int*)g,
        (__attribute__((address_space(3))) unsigned int*)lds_base_uniform,
        16, 0, 0);
}

// ---------------------------------------------------------------------------
// f32 -> bf16 conversion (vectorized, n % 4 == 0)
// ---------------------------------------------------------------------------
__global__ __launch_bounds__(256) void cvt_f32_bf16(const float* __restrict__ in,
                                                    unsigned short* __restrict__ out, int n) {
    int i = blockIdx.x * blockDim.x + threadIdx.x;
    if (i * 4 >= n) return;
    float4 v = reinterpret_cast<const float4*>(in)[i];
    us4 o = { f2b(v.x), f2b(v.y), f2b(v.z), f2b(v.w) };
    reinterpret_cast<us4*>(out)[i] = o;
}

// ---------------------------------------------------------------------------
// bf16 MFMA GEMM (m97 structure, single-buffered), 128x128 tile, BK=32.
// ---------------------------------------------------------------------------
#define BM 128
#define BN 128
#define BK 32

template <bool BF16OUT>
__global__ __launch_bounds__(256) void gemm_bt_mfma(const unsigned short* __restrict__ A,
                                                    const unsigned short* __restrict__ B,
                                                    void* __restrict__ Cout,
                                                    int M, int N, int K) {
    __shared__ unsigned short As[BM * BK];   // 8 KB
    __shared__ unsigned short Bs[BN * BK];   // 8 KB
    const int tid  = threadIdx.x;
    const int lane = tid & 63, wid = tid >> 6;
    const int wr = wid >> 1, wc = wid & 1;
    const int lm = lane & 15, lg = lane >> 4;
    const int brow = blockIdx.y * BM, bcol = blockIdx.x * BN;

    f32x4 acc[4][4] = {};

    const int rA  = tid >> 2;
    const int kc8 = (tid & 3) * 8;
    const unsigned short* gA0 = A + (size_t)(brow + rA) * K + kc8;
    const unsigned short* gA1 = A + (size_t)(brow + 64 + rA) * K + kc8;
    const unsigned short* gB0 = B + (size_t)(bcol + rA) * K + kc8;
    const unsigned short* gB1 = B + (size_t)(bcol + 64 + rA) * K + kc8;
    unsigned short* lA0 = As + wid * 512;
    unsigned short* lA1 = As + 2048 + wid * 512;
    unsigned short* lB0 = Bs + wid * 512;
    unsigned short* lB1 = Bs + 2048 + wid * 512;

    for (int k0 = 0; k0 < K; k0 += BK) {
        gload_lds16(gA0 + k0, lA0);
        gload_lds16(gA1 + k0, lA1);
        gload_lds16(gB0 + k0, lB0);
        gload_lds16(gB1 + k0, lB1);
        __syncthreads();

        short8 a[4], b[4];
#pragma unroll
        for (int m = 0; m < 4; ++m)
            a[m] = *reinterpret_cast<const short8*>(&As[(wr * 64 + m * 16 + lm) * BK + lg * 8]);
#pragma unroll
        for (int n = 0; n < 4; ++n)
            b[n] = *reinterpret_cast<const short8*>(&Bs[(wc * 64 + n * 16 + lm) * BK + lg * 8]);
#pragma unroll
        for (int m = 0; m < 4; ++m)
#pragma unroll
            for (int n = 0; n < 4; ++n)
                acc[m][n] = __builtin_amdgcn_mfma_f32_16x16x32_bf16(a[m], b[n], acc[m][n], 0, 0, 0);
        __syncthreads();
    }

#pragma unroll
    for (int m = 0; m < 4; ++m) {
#pragma unroll
        for (int r = 0; r < 4; ++r) {
            const size_t base = (size_t)(brow + wr * 64 + m * 16 + lg * 4 + r) * N + bcol + wc * 64 + lm;
#pragma unroll
            for (int n = 0; n < 4; ++n) {
                if (BF16OUT)
                    ((unsigned short*)Cout)[base + n * 16] = f2b(acc[m][n][r]);
                else
                    ((float*)Cout)[base + n * 16] = acc[m][n][r];
            }
        }
    }
}

// ---------------------------------------------------------------------------
// RoPE in place on bf16 q,k. q additionally scaled by log2(e)/sqrt(DH)
// (scores then live in the exp2 domain -> bare v_exp_f32 in softmax).
// ---------------------------------------------------------------------------
__global__ __launch_bounds__(256) void rope_qk_bf16(unsigned short* __restrict__ q,
                                                    unsigned short* __restrict__ k,
                                                    int total) {
    int idx = blockIdx.x * blockDim.x + threadIdx.x;
    if (idx >= total) return;
    int i = idx & 31;
    int s = (idx >> 9) & (SEQ - 1);
    float inv = powf(10000.0f, -2.0f * (float)i / (float)DH);
    float ang = (float)s * inv;
    float c = cosf(ang), sn = sinf(ang);
    size_t off = ((size_t)(idx >> 5)) * 64 + 2 * i;
    const float scale = 0.125f * 1.4426950408889634f;   // 1/sqrt(64) * log2(e)
    float qe = b2f(q[off]), qo = b2f(q[off + 1]);
    q[off]     = f2b((qe * c - qo * sn) * scale);
    q[off + 1] = f2b((qe * sn + qo * c) * scale);
    float ke = b2f(k[off]), ko = b2f(k[off + 1]);
    k[off]     = f2b(ke * c - ko * sn);
    k[off + 1] = f2b(ke * sn + ko * c);
}

// ---------------------------------------------------------------------------
// Transpose V: [b, s, h, d] -> vT[(b*NH+h)*DH + d][s]   (bf16)
// ---------------------------------------------------------------------------
__global__ __launch_bounds__(256) void transpose_v(const unsigned short* __restrict__ v,
                                                   unsigned short* __restrict__ vT) {
    __shared__ unsigned short t[64][68];
    const int s0 = blockIdx.x * 64;
    const int bh = blockIdx.y;
    const int b = bh >> 4, h = bh & 15;
    const int tid = threadIdx.x;
    for (int idx = tid; idx < 1024; idx += 256) {
        int s = idx >> 4;
        int dg = (idx & 15) * 4;
        us4 val = *reinterpret_cast<const us4*>(v + (size_t)(b * SEQ + s0 + s) * DM + h * DH + dg);
        *reinterpret_cast<us4*>(&t[s][dg]) = val;
    }
    __syncthreads();
    for (int idx = tid; idx < 1024; idx += 256) {
        int d = idx >> 4;
        int sg = (idx & 15) * 4;
        us4 val;
        val.x = t[sg + 0][d];
        val.y = t[sg + 1][d];
        val.z = t[sg + 2][d];
        val.w = t[sg + 3][d];
        *reinterpret_cast<us4*>(vT + (size_t)(bh * DH + d) * SEQ + s0 + sg) = val;
    }
}

// ---------------------------------------------------------------------------
// MFMA flash attention v2.
// 4 waves/block; wave w owns the 16-query tile at blockIdx.x*64 + w*16.
// KVBLK = 64 keys/iter (4 QK sub-tiles -> independent MFMA chains).
// Per-wave LDS P buffer; no __syncthreads (wave trip counts differ).
// Scores arrive in exp2 domain (Q pre-scaled by log2e/8).
// ---------------------------------------------------------------------------
__global__ __launch_bounds__(256, 4) void attn_mfma(const unsigned short* __restrict__ qbf,
                                                    const unsigned short* __restrict__ kbf,
                                                    const unsigned short* __restrict__ vT,
                                                    unsigned short* __restrict__ o) {
    const int tid  = threadIdx.x;
    const int wid  = tid >> 6;
    const int lane = tid & 63;
    const int lm = lane & 15, lg = lane >> 4;
    const int bh = blockIdx.y;
    const int b = bh >> 4, h = bh & 15;
    const int qbase = blockIdx.x * 64 + wid * 16;

    __shared__ unsigned short Pl[4][16][72];   // per-wave P tile, 16B-aligned rows
    unsigned short (*P)[72] = Pl[wid];

    const unsigned short* qrow = qbf + ((size_t)(b * SEQ + qbase + lm)) * DM + h * DH;
    short8 qa0 = *reinterpret_cast<const short8*>(qrow + lg * 8);
    short8 qa1 = *reinterpret_cast<const short8*>(qrow + 32 + lg * 8);

    const unsigned short* kb = kbf + ((size_t)b * SEQ) * DM + h * DH;
    const unsigned short* vb = vT + ((size_t)bh) * DH * SEQ;

    f32x4 o0 = {0.f, 0.f, 0.f, 0.f}, o1 = o0, o2 = o0, o3 = o0;
    float m[4] = {-INFINITY, -INFINITY, -INFINITY, -INFINITY};
    float l[4] = {0.f, 0.f, 0.f, 0.f};

    const int nb = (qbase + 79) >> 6;          // 64-key blocks; only last needs mask
    for (int blk = 0; blk < nb; ++blk) {
        const int kbase = blk << 6;

        // QK^T: 4 independent sub-tiles of 16 keys
        f32x4 s[4];
#pragma unroll
        for (int st = 0; st < 4; ++st) {
            const unsigned short* kr = kb + (size_t)(kbase + st * 16 + lm) * DM;
            short8 k0 = *reinterpret_cast<const short8*>(kr + lg * 8);
            short8 k1 = *reinterpret_cast<const short8*>(kr + 32 + lg * 8);
            f32x4 t = {0.f, 0.f, 0.f, 0.f};
            t = __builtin_amdgcn_mfma_f32_16x16x32_bf16(qa0, k0, t, 0, 0, 0);
            t = __builtin_amdgcn_mfma_f32_16x16x32_bf16(qa1, k1, t, 0, 0, 0);
            s[st] = t;
        }

        if (blk == nb - 1) {
#pragma unroll
            for (int st = 0; st < 4; ++st)
#pragma unroll
                for (int r = 0; r < 4; ++r) {
                    int qg = qbase + lg * 4 + r;
                    s[st][r] = (kbase + st * 16 + lm <= qg) ? s[st][r] : -INFINITY;
                }
        }

        // online softmax (exp2 domain), rows q = qbase + lg*4 + r
        float f[4];
#pragma unroll
        for (int r = 0; r < 4; ++r) {
            float mx = fmaxf(fmaxf(s[0][r], s[1][r]), fmaxf(s[2][r], s[3][r]));
#pragma unroll
            for (int off = 1; off < 16; off <<= 1)
                mx = fmaxf(mx, __shfl_xor(mx, off));
            float mn = fmaxf(m[r], mx);
            f[r] = exp2f(m[r] - mn);
            m[r] = mn;
            float ps = 0.f;
#pragma unroll
            for (int st = 0; st < 4; ++st) {
                float p = exp2f(s[st][r] - mn);
                s[st][r] = p;
                ps += p;
            }
#pragma unroll
            for (int off = 1; off < 16; off <<= 1)
                ps += __shfl_xor(ps, off);
            l[r] = l[r] * f[r] + ps;
        }
#pragma unroll
        for (int r = 0; r < 4; ++r) {
            o0[r] *= f[r]; o1[r] *= f[r]; o2[r] *= f[r]; o3[r] *= f[r];
        }

        // stage P (bf16) to per-wave LDS: P[q - qbase][k - kbase]
#pragma unroll
        for (int st = 0; st < 4; ++st)
#pragma unroll
            for (int r = 0; r < 4; ++r)
                P[lg * 4 + r][st * 16 + lm] = f2b(s[st][r]);

        // wave-local write->read ordering: LDS pipe is in-order per wave;
        // barrier stops compiler reordering.
        __builtin_amdgcn_wave_barrier();
        asm volatile("" ::: "memory");

        short8 pa0 = *reinterpret_cast<const short8*>(&P[lm][lg * 8]);
        short8 pa1 = *reinterpret_cast<const short8*>(&P[lm][32 + lg * 8]);

        __builtin_amdgcn_wave_barrier();
        asm volatile("" ::: "memory");

        // PV: O[q][d], 4 chunks of 16 d-cols, k = 64 via 2 MFMAs each
#pragma unroll
        for (int c = 0; c < 4; ++c) {
            const unsigned short* vr = vb + (size_t)(c * 16 + lm) * SEQ + kbase;
            short8 v0 = *reinterpret_cast<const short8*>(vr + lg * 8);
            short8 v1 = *reinterpret_cast<const short8*>(vr + 32 + lg * 8);
            f32x4* oc = (c == 0) ? &o0 : (c == 1) ? &o1 : (c == 2) ? &o2 : &o3;
            *oc = __builtin_amdgcn_mfma_f32_16x16x32_bf16(pa0, v0, *oc, 0, 0, 0);
            *oc = __builtin_amdgcn_mfma_f32_16x16x32_bf16(pa1, v1, *oc, 0, 0, 0);
        }
    }

#pragma unroll
    for (int r = 0; r < 4; ++r) {
        const size_t rowoff = ((size_t)(b * SEQ + qbase + lg * 4 + r)) * DM + h * DH;
        const float inv_l = 1.0f / l[r];
        o[rowoff + 0 * 16 + lm] = f2b(o0[r] * inv_l);
        o[rowoff + 1 * 16 + lm] = f2b(o1[r] * inv_l);
        o[rowoff + 2 * 16 + lm] = f2b(o2[r] * inv_l);
        o[rowoff + 3 * 16 + lm] = f2b(o3[r] * inv_l);
    }
}

// ---------------------------------------------------------------------------
extern "C" void kernel_launch(void* const* d_in, const int* in_sizes, int n_in,
                              void* d_out, int out_size, void* d_ws, size_t ws_size,
                              hipStream_t stream) {
    const float* x  = (const float*)d_in[0];
    const float* wq = (const float*)d_in[1];
    const float* wk = (const float*)d_in[2];
    const float* wv = (const float*)d_in[3];
    const float* wo = (const float*)d_in[4];
    float* out = (float*)d_out;

    const int TSZ = MROWS * DM;      // 4M
    const int WSZ = DM * DM;         // 1M
    char* ws = (char*)d_ws;
    const size_t MB = 1024 * 1024;
    unsigned short* xb      = (unsigned short*)(ws);             // 8 MB
    unsigned short* wqb     = (unsigned short*)(ws + 8 * MB);    // 2 MB each
    unsigned short* wkb     = (unsigned short*)(ws + 10 * MB);
    unsigned short* wvb     = (unsigned short*)(ws + 12 * MB);
    unsigned short* wob     = (unsigned short*)(ws + 14 * MB);
    unsigned short* qbf     = (unsigned short*)(ws + 16 * MB);   // 8 MB
    unsigned short* kbf     = (unsigned short*)(ws + 24 * MB);   // 8 MB
    unsigned short* vtmp    = (unsigned short*)(ws + 32 * MB);   // 8 MB
    unsigned short* vT      = (unsigned short*)(ws + 40 * MB);   // 8 MB
    unsigned short* attn_bf = (unsigned short*)(ws + 32 * MB);   // reuse vtmp after transpose

    cvt_f32_bf16<<<TSZ / 4 / 256, 256, 0, stream>>>(x, xb, TSZ);
    cvt_f32_bf16<<<WSZ / 4 / 256, 256, 0, stream>>>(wq, wqb, WSZ);
    cvt_f32_bf16<<<WSZ / 4 / 256, 256, 0, stream>>>(wk, wkb, WSZ);
    cvt_f32_bf16<<<WSZ / 4 / 256, 256, 0, stream>>>(wv, wvb, WSZ);
    cvt_f32_bf16<<<WSZ / 4 / 256, 256, 0, stream>>>(wo, wob, WSZ);

    dim3 grd(DM / BN, MROWS / BM);   // (8, 32)
    gemm_bt_mfma<true><<<grd, 256, 0, stream>>>(xb, wqb, qbf,  MROWS, DM, DM);
    gemm_bt_mfma<true><<<grd, 256, 0, stream>>>(xb, wkb, kbf,  MROWS, DM, DM);
    gemm_bt_mfma<true><<<grd, 256, 0, stream>>>(xb, wvb, vtmp, MROWS, DM, DM);

    int total = MROWS * NH * 32;
    rope_qk_bf16<<<(total + 255) / 256, 256, 0, stream>>>(qbf, kbf, total);

    transpose_v<<<dim3(SEQ / 64, B_SZ * NH), 256, 0, stream>>>(vtmp, vT);

    attn_mfma<<<dim3(SEQ / 64, B_SZ * NH), 256, 0, stream>>>(qbf, kbf, vT, attn_bf);

    gemm_bt_mfma<false><<<grd, 256, 0, stream>>>(attn_bf, wob, out, MROWS, DM, DM);
}

// Round 5
// 319.290 us; speedup vs baseline: 20.9508x; 1.1836x over previous
//
#include <hip/hip_runtime.h>
#include <math.h>

// Problem constants
#define B_SZ   2
#define SEQ    2048
#define DM     1024
#define NH     16
#define DH     64
#define MROWS  (B_SZ * SEQ)      // 4096

typedef __attribute__((ext_vector_type(8))) short short8;
typedef __attribute__((ext_vector_type(4))) float f32x4;
typedef __attribute__((ext_vector_type(4))) unsigned short us4;

__device__ __forceinline__ float b2f(unsigned short u) {
    union { float f; unsigned int i; } x; x.i = ((unsigned int)u) << 16; return x.f;
}
__device__ __forceinline__ unsigned short f2b(float f) {
    union { float f; unsigned int i; } x; x.f = f;
    return (unsigned short)((x.i + 0x7fffu + ((x.i >> 16) & 1u)) >> 16);
}

// async global->LDS, 16B per lane; lds base must be wave-uniform (HW adds lane*16)
__device__ __forceinline__ void gload_lds16(const unsigned short* g, unsigned short* lds_base_uniform) {
    __builtin_amdgcn_global_load_lds(
        (const __attribute__((address_space(1))) unsigned int*)g,
        (__attribute__((address_space(3))) unsigned int*)lds_base_uniform,
        16, 0, 0);
}

// ---------------------------------------------------------------------------
// f32 -> bf16 conversion (vectorized, n % 4 == 0)
// ---------------------------------------------------------------------------
__global__ __launch_bounds__(256) void cvt_f32_bf16(const float* __restrict__ in,
                                                    unsigned short* __restrict__ out, int n) {
    int i = blockIdx.x * blockDim.x + threadIdx.x;
    if (i * 4 >= n) return;
    float4 v = reinterpret_cast<const float4*>(in)[i];
    us4 o = { f2b(v.x), f2b(v.y), f2b(v.z), f2b(v.w) };
    reinterpret_cast<us4*>(out)[i] = o;
}

// ---------------------------------------------------------------------------
// bf16 MFMA GEMM (m97 structure, single-buffered), 128x128 tile, BK=32.
// ---------------------------------------------------------------------------
#define BM 128
#define BN 128
#define BK 32

template <bool BF16OUT>
__global__ __launch_bounds__(256) void gemm_bt_mfma(const unsigned short* __restrict__ A,
                                                    const unsigned short* __restrict__ B,
                                                    void* __restrict__ Cout,
                                                    int M, int N, int K) {
    __shared__ unsigned short As[BM * BK];   // 8 KB
    __shared__ unsigned short Bs[BN * BK];   // 8 KB
    const int tid  = threadIdx.x;
    const int lane = tid & 63, wid = tid >> 6;
    const int wr = wid >> 1, wc = wid & 1;
    const int lm = lane & 15, lg = lane >> 4;
    const int brow = blockIdx.y * BM, bcol = blockIdx.x * BN;

    f32x4 acc[4][4] = {};

    const int rA  = tid >> 2;
    const int kc8 = (tid & 3) * 8;
    const unsigned short* gA0 = A + (size_t)(brow + rA) * K + kc8;
    const unsigned short* gA1 = A + (size_t)(brow + 64 + rA) * K + kc8;
    const unsigned short* gB0 = B + (size_t)(bcol + rA) * K + kc8;
    const unsigned short* gB1 = B + (size_t)(bcol + 64 + rA) * K + kc8;
    unsigned short* lA0 = As + wid * 512;
    unsigned short* lA1 = As + 2048 + wid * 512;
    unsigned short* lB0 = Bs + wid * 512;
    unsigned short* lB1 = Bs + 2048 + wid * 512;

    for (int k0 = 0; k0 < K; k0 += BK) {
        gload_lds16(gA0 + k0, lA0);
        gload_lds16(gA1 + k0, lA1);
        gload_lds16(gB0 + k0, lB0);
        gload_lds16(gB1 + k0, lB1);
        __syncthreads();

        short8 a[4], b[4];
#pragma unroll
        for (int m = 0; m < 4; ++m)
            a[m] = *reinterpret_cast<const short8*>(&As[(wr * 64 + m * 16 + lm) * BK + lg * 8]);
#pragma unroll
        for (int n = 0; n < 4; ++n)
            b[n] = *reinterpret_cast<const short8*>(&Bs[(wc * 64 + n * 16 + lm) * BK + lg * 8]);
#pragma unroll
        for (int m = 0; m < 4; ++m)
#pragma unroll
            for (int n = 0; n < 4; ++n)
                acc[m][n] = __builtin_amdgcn_mfma_f32_16x16x32_bf16(a[m], b[n], acc[m][n], 0, 0, 0);
        __syncthreads();
    }

#pragma unroll
    for (int m = 0; m < 4; ++m) {
#pragma unroll
        for (int r = 0; r < 4; ++r) {
            const size_t base = (size_t)(brow + wr * 64 + m * 16 + lg * 4 + r) * N + bcol + wc * 64 + lm;
#pragma unroll
            for (int n = 0; n < 4; ++n) {
                if (BF16OUT)
                    ((unsigned short*)Cout)[base + n * 16] = f2b(acc[m][n][r]);
                else
                    ((float*)Cout)[base + n * 16] = acc[m][n][r];
            }
        }
    }
}

// ---------------------------------------------------------------------------
// RoPE cos/sin table: tab[s*32 + i] = {cos,sin}(s * theta^(-2i/64))
// ---------------------------------------------------------------------------
__global__ __launch_bounds__(256) void rope_tables(float* __restrict__ tab) {
    int idx = blockIdx.x * blockDim.x + threadIdx.x;   // SEQ*32 total
    int s = idx >> 5, i = idx & 31;
    float inv = powf(10000.0f, -2.0f * (float)i / (float)DH);
    float ang = (float)s * inv;
    tab[idx * 2]     = cosf(ang);
    tab[idx * 2 + 1] = sinf(ang);
}

// ---------------------------------------------------------------------------
// RoPE in place on bf16 q,k via table. q additionally scaled by log2(e)/sqrt(DH).
// ---------------------------------------------------------------------------
__global__ __launch_bounds__(256) void rope_qk_bf16(unsigned short* __restrict__ q,
                                                    unsigned short* __restrict__ k,
                                                    const float* __restrict__ tab,
                                                    int total) {
    int idx = blockIdx.x * blockDim.x + threadIdx.x;
    if (idx >= total) return;
    int i = idx & 31;
    int s = (idx >> 9) & (SEQ - 1);
    float2 cs = reinterpret_cast<const float2*>(tab)[s * 32 + i];
    float c = cs.x, sn = cs.y;
    size_t off = ((size_t)(idx >> 5)) * 64 + 2 * i;
    const float scale = 0.125f * 1.4426950408889634f;   // 1/sqrt(64) * log2(e)
    float qe = b2f(q[off]), qo = b2f(q[off + 1]);
    q[off]     = f2b((qe * c - qo * sn) * scale);
    q[off + 1] = f2b((qe * sn + qo * c) * scale);
    float ke = b2f(k[off]), ko = b2f(k[off + 1]);
    k[off]     = f2b(ke * c - ko * sn);
    k[off + 1] = f2b(ke * sn + ko * c);
}

// ---------------------------------------------------------------------------
// Transpose V: [b, s, h, d] -> vT[(b*NH+h)*DH + d][s]   (bf16)
// ---------------------------------------------------------------------------
__global__ __launch_bounds__(256) void transpose_v(const unsigned short* __restrict__ v,
                                                   unsigned short* __restrict__ vT) {
    __shared__ unsigned short t[64][68];
    const int s0 = blockIdx.x * 64;
    const int bh = blockIdx.y;
    const int b = bh >> 4, h = bh & 15;
    const int tid = threadIdx.x;
    for (int idx = tid; idx < 1024; idx += 256) {
        int s = idx >> 4;
        int dg = (idx & 15) * 4;
        us4 val = *reinterpret_cast<const us4*>(v + (size_t)(b * SEQ + s0 + s) * DM + h * DH + dg);
        *reinterpret_cast<us4*>(&t[s][dg]) = val;
    }
    __syncthreads();
    for (int idx = tid; idx < 1024; idx += 256) {
        int d = idx >> 4;
        int sg = (idx & 15) * 4;
        us4 val;
        val.x = t[sg + 0][d];
        val.y = t[sg + 1][d];
        val.z = t[sg + 2][d];
        val.w = t[sg + 3][d];
        *reinterpret_cast<us4*>(vT + (size_t)(bh * DH + d) * SEQ + s0 + sg) = val;
    }
}

// ---------------------------------------------------------------------------
// MFMA flash attention v3.
// 1D grid, XCD-locality swizzle: bid = (bh&7) + 8*slot so each XCD serves
// only 4 bh's (2MB K/V working set fits the 4MB XCD L2).
// Longest-first qchunk order for causal load balance.
// 4 waves/block, wave w owns 16-query tile. KVBLK=64.
// V loads issued before softmax; next K prefetched before PV (issue-early).
// Scores in exp2 domain (Q pre-scaled by log2e/8).
// ---------------------------------------------------------------------------
#define LOADK(kbase, dst)                                                              \
    {                                                                                  \
        _Pragma("unroll")                                                              \
        for (int st = 0; st < 4; ++st) {                                               \
            const unsigned short* kr = kb + (size_t)((kbase) + st * 16 + lm) * DM;     \
            dst[st * 2]     = *reinterpret_cast<const short8*>(kr + lg * 8);           \
            dst[st * 2 + 1] = *reinterpret_cast<const short8*>(kr + 32 + lg * 8);      \
        }                                                                              \
    }

__global__ __launch_bounds__(256, 3) void attn_mfma(const unsigned short* __restrict__ qbf,
                                                    const unsigned short* __restrict__ kbf,
                                                    const unsigned short* __restrict__ vT,
                                                    unsigned short* __restrict__ o) {
    const int tid  = threadIdx.x;
    const int wid  = tid >> 6;
    const int lane = tid & 63;
    const int lm = lane & 15, lg = lane >> 4;

    // swizzled decode: xcd = bid & 7 (HW round-robin), bh locked to xcd group
    const int bid    = blockIdx.x;
    const int slot   = bid >> 3;                 // 0..127
    const int bh     = (bid & 7) + 8 * (slot >> 5);
    const int qchunk = 31 - (slot & 31);         // longest first
    const int b = bh >> 4, h = bh & 15;
    const int qbase = qchunk * 64 + wid * 16;

    __shared__ unsigned short Pl[4][16][72];
    unsigned short (*P)[72] = Pl[wid];

    const unsigned short* qrow = qbf + ((size_t)(b * SEQ + qbase + lm)) * DM + h * DH;
    short8 qa0 = *reinterpret_cast<const short8*>(qrow + lg * 8);
    short8 qa1 = *reinterpret_cast<const short8*>(qrow + 32 + lg * 8);

    const unsigned short* kb = kbf + ((size_t)b * SEQ) * DM + h * DH;
    const unsigned short* vb = vT + ((size_t)bh) * DH * SEQ;

    f32x4 o0 = {0.f, 0.f, 0.f, 0.f}, o1 = o0, o2 = o0, o3 = o0;
    float m[4] = {-INFINITY, -INFINITY, -INFINITY, -INFINITY};
    float l[4] = {0.f, 0.f, 0.f, 0.f};

    const int nb = (qbase + 79) >> 6;
    short8 kc[8], kn[8];
    LOADK(0, kc);

    for (int blk = 0; blk < nb; ++blk) {
        const int kbase = blk << 6;

        // V first half issued early (consumed at PV, hidden under QK+softmax)
        short8 vvA[4];
#pragma unroll
        for (int c = 0; c < 2; ++c) {
            const unsigned short* vr = vb + (size_t)(c * 16 + lm) * SEQ + kbase;
            vvA[c * 2]     = *reinterpret_cast<const short8*>(vr + lg * 8);
            vvA[c * 2 + 1] = *reinterpret_cast<const short8*>(vr + 32 + lg * 8);
        }

        // QK^T: 4 independent sub-tiles of 16 keys
        f32x4 s[4];
#pragma unroll
        for (int st = 0; st < 4; ++st) {
            f32x4 t = {0.f, 0.f, 0.f, 0.f};
            t = __builtin_amdgcn_mfma_f32_16x16x32_bf16(qa0, kc[st * 2],     t, 0, 0, 0);
            t = __builtin_amdgcn_mfma_f32_16x16x32_bf16(qa1, kc[st * 2 + 1], t, 0, 0, 0);
            s[st] = t;
        }

        // prefetch next K (consumed next iteration)
        if (blk + 1 < nb) LOADK((blk + 1) << 6, kn);

        if (blk == nb - 1) {
#pragma unroll
            for (int st = 0; st < 4; ++st)
#pragma unroll
                for (int r = 0; r < 4; ++r) {
                    int qg = qbase + lg * 4 + r;
                    s[st][r] = (kbase + st * 16 + lm <= qg) ? s[st][r] : -INFINITY;
                }
        }

        // online softmax (exp2 domain)
        float f[4];
#pragma unroll
        for (int r = 0; r < 4; ++r) {
            float mx = fmaxf(fmaxf(s[0][r], s[1][r]), fmaxf(s[2][r], s[3][r]));
#pragma unroll
            for (int off = 1; off < 16; off <<= 1)
                mx = fmaxf(mx, __shfl_xor(mx, off));
            float mn = fmaxf(m[r], mx);
            f[r] = exp2f(m[r] - mn);
            m[r] = mn;
            float ps = 0.f;
#pragma unroll
            for (int st = 0; st < 4; ++st) {
                float p = exp2f(s[st][r] - mn);
                s[st][r] = p;
                ps += p;
            }
#pragma unroll
            for (int off = 1; off < 16; off <<= 1)
                ps += __shfl_xor(ps, off);
            l[r] = l[r] * f[r] + ps;
        }
#pragma unroll
        for (int r = 0; r < 4; ++r) {
            o0[r] *= f[r]; o1[r] *= f[r]; o2[r] *= f[r]; o3[r] *= f[r];
        }

        // stage P (bf16) to per-wave LDS
#pragma unroll
        for (int st = 0; st < 4; ++st)
#pragma unroll
            for (int r = 0; r < 4; ++r)
                P[lg * 4 + r][st * 16 + lm] = f2b(s[st][r]);

        __builtin_amdgcn_wave_barrier();
        asm volatile("" ::: "memory");

        short8 pa0 = *reinterpret_cast<const short8*>(&P[lm][lg * 8]);
        short8 pa1 = *reinterpret_cast<const short8*>(&P[lm][32 + lg * 8]);

        __builtin_amdgcn_wave_barrier();
        asm volatile("" ::: "memory");

        // V second half issued here (consumed ~200cy later at PV c=2,3)
        short8 vvB[4];
#pragma unroll
        for (int c = 0; c < 2; ++c) {
            const unsigned short* vr = vb + (size_t)((c + 2) * 16 + lm) * SEQ + kbase;
            vvB[c * 2]     = *reinterpret_cast<const short8*>(vr + lg * 8);
            vvB[c * 2 + 1] = *reinterpret_cast<const short8*>(vr + 32 + lg * 8);
        }

        o0 = __builtin_amdgcn_mfma_f32_16x16x32_bf16(pa0, vvA[0], o0, 0, 0, 0);
        o0 = __builtin_amdgcn_mfma_f32_16x16x32_bf16(pa1, vvA[1], o0, 0, 0, 0);
        o1 = __builtin_amdgcn_mfma_f32_16x16x32_bf16(pa0, vvA[2], o1, 0, 0, 0);
        o1 = __builtin_amdgcn_mfma_f32_16x16x32_bf16(pa1, vvA[3], o1, 0, 0, 0);
        o2 = __builtin_amdgcn_mfma_f32_16x16x32_bf16(pa0, vvB[0], o2, 0, 0, 0);
        o2 = __builtin_amdgcn_mfma_f32_16x16x32_bf16(pa1, vvB[1], o2, 0, 0, 0);
        o3 = __builtin_amdgcn_mfma_f32_16x16x32_bf16(pa0, vvB[2], o3, 0, 0, 0);
        o3 = __builtin_amdgcn_mfma_f32_16x16x32_bf16(pa1, vvB[3], o3, 0, 0, 0);

        if (blk + 1 < nb) {
#pragma unroll
            for (int i = 0; i < 8; ++i) kc[i] = kn[i];
        }
    }

#pragma unroll
    for (int r = 0; r < 4; ++r) {
        const size_t rowoff = ((size_t)(b * SEQ + qbase + lg * 4 + r)) * DM + h * DH;
        const float inv_l = 1.0f / l[r];
        o[rowoff + 0 * 16 + lm] = f2b(o0[r] * inv_l);
        o[rowoff + 1 * 16 + lm] = f2b(o1[r] * inv_l);
        o[rowoff + 2 * 16 + lm] = f2b(o2[r] * inv_l);
        o[rowoff + 3 * 16 + lm] = f2b(o3[r] * inv_l);
    }
}

// ---------------------------------------------------------------------------
extern "C" void kernel_launch(void* const* d_in, const int* in_sizes, int n_in,
                              void* d_out, int out_size, void* d_ws, size_t ws_size,
                              hipStream_t stream) {
    const float* x  = (const float*)d_in[0];
    const float* wq = (const float*)d_in[1];
    const float* wk = (const float*)d_in[2];
    const float* wv = (const float*)d_in[3];
    const float* wo = (const float*)d_in[4];
    float* out = (float*)d_out;

    const int TSZ = MROWS * DM;      // 4M
    const int WSZ = DM * DM;         // 1M
    char* ws = (char*)d_ws;
    const size_t MB = 1024 * 1024;
    unsigned short* xb      = (unsigned short*)(ws);             // 8 MB
    unsigned short* wqb     = (unsigned short*)(ws + 8 * MB);    // 2 MB each
    unsigned short* wkb     = (unsigned short*)(ws + 10 * MB);
    unsigned short* wvb     = (unsigned short*)(ws + 12 * MB);
    unsigned short* wob     = (unsigned short*)(ws + 14 * MB);
    unsigned short* qbf     = (unsigned short*)(ws + 16 * MB);   // 8 MB
    unsigned short* kbf     = (unsigned short*)(ws + 24 * MB);   // 8 MB
    unsigned short* vtmp    = (unsigned short*)(ws + 32 * MB);   // 8 MB
    unsigned short* vT      = (unsigned short*)(ws + 40 * MB);   // 8 MB
    unsigned short* attn_bf = (unsigned short*)(ws + 32 * MB);   // reuse vtmp after transpose
    float*          ropetab = (float*)(ws + 40 * MB);            // reuse vT region pre-transpose

    cvt_f32_bf16<<<TSZ / 4 / 256, 256, 0, stream>>>(x, xb, TSZ);
    cvt_f32_bf16<<<WSZ / 4 / 256, 256, 0, stream>>>(wq, wqb, WSZ);
    cvt_f32_bf16<<<WSZ / 4 / 256, 256, 0, stream>>>(wk, wkb, WSZ);
    cvt_f32_bf16<<<WSZ / 4 / 256, 256, 0, stream>>>(wv, wvb, WSZ);
    cvt_f32_bf16<<<WSZ / 4 / 256, 256, 0, stream>>>(wo, wob, WSZ);

    dim3 grd(DM / BN, MROWS / BM);   // (8, 32)
    gemm_bt_mfma<true><<<grd, 256, 0, stream>>>(xb, wqb, qbf,  MROWS, DM, DM);
    gemm_bt_mfma<true><<<grd, 256, 0, stream>>>(xb, wkb, kbf,  MROWS, DM, DM);
    gemm_bt_mfma<true><<<grd, 256, 0, stream>>>(xb, wvb, vtmp, MROWS, DM, DM);

    rope_tables<<<SEQ * 32 / 256, 256, 0, stream>>>(ropetab);
    int total = MROWS * NH * 32;
    rope_qk_bf16<<<(total + 255) / 256, 256, 0, stream>>>(qbf, kbf, ropetab, total);

    transpose_v<<<dim3(SEQ / 64, B_SZ * NH), 256, 0, stream>>>(vtmp, vT);

    attn_mfma<<<1024, 256, 0, stream>>>(qbf, kbf, vT, attn_bf);

    gemm_bt_mfma<false><<<grd, 256, 0, stream>>>(attn_bf, wob, out, MROWS, DM, DM);
}

// Round 6
// 267.128 us; speedup vs baseline: 25.0418x; 1.1953x over previous
//
#include <hip/hip_runtime.h>
#include <math.h>

// Problem constants
#define B_SZ   2
#define SEQ    2048
#define DM     1024
#define NH     16
#define DH     64
#define MROWS  (B_SZ * SEQ)      // 4096

typedef __attribute__((ext_vector_type(8))) short short8;
typedef __attribute__((ext_vector_type(4))) float f32x4;
typedef __attribute__((ext_vector_type(4))) unsigned short us4;
typedef __attribute__((ext_vector_type(2))) unsigned int u32x2;

__device__ __forceinline__ float b2f(unsigned short u) {
    union { float f; unsigned int i; } x; x.i = ((unsigned int)u) << 16; return x.f;
}
__device__ __forceinline__ unsigned short f2b(float f) {
    union { float f; unsigned int i; } x; x.f = f;
    return (unsigned short)((x.i + 0x7fffu + ((x.i >> 16) & 1u)) >> 16);
}

// async global->LDS, 16B per lane; lds base must be wave-uniform (HW adds lane*16)
__device__ __forceinline__ void gload_lds16(const unsigned short* g, unsigned short* lds_base_uniform) {
    __builtin_amdgcn_global_load_lds(
        (const __attribute__((address_space(1))) unsigned int*)g,
        (__attribute__((address_space(3))) unsigned int*)lds_base_uniform,
        16, 0, 0);
}

// ---------------------------------------------------------------------------
// f32 -> bf16 conversion (vectorized, n % 4 == 0)
// ---------------------------------------------------------------------------
__global__ __launch_bounds__(256) void cvt_f32_bf16(const float* __restrict__ in,
                                                    unsigned short* __restrict__ out, int n) {
    int i = blockIdx.x * blockDim.x + threadIdx.x;
    if (i * 4 >= n) return;
    float4 v = reinterpret_cast<const float4*>(in)[i];
    us4 o = { f2b(v.x), f2b(v.y), f2b(v.z), f2b(v.w) };
    reinterpret_cast<us4*>(out)[i] = o;
}

// ---------------------------------------------------------------------------
// bf16 MFMA GEMM (m97 structure, single-buffered), 128x128 tile, BK=32.
// ---------------------------------------------------------------------------
#define BM 128
#define BN 128
#define BK 32

template <bool BF16OUT>
__global__ __launch_bounds__(256) void gemm_bt_mfma(const unsigned short* __restrict__ A,
                                                    const unsigned short* __restrict__ B,
                                                    void* __restrict__ Cout,
                                                    int M, int N, int K) {
    __shared__ unsigned short As[BM * BK];   // 8 KB
    __shared__ unsigned short Bs[BN * BK];   // 8 KB
    const int tid  = threadIdx.x;
    const int lane = tid & 63, wid = tid >> 6;
    const int wr = wid >> 1, wc = wid & 1;
    const int lm = lane & 15, lg = lane >> 4;
    const int brow = blockIdx.y * BM, bcol = blockIdx.x * BN;

    f32x4 acc[4][4] = {};

    const int rA  = tid >> 2;
    const int kc8 = (tid & 3) * 8;
    const unsigned short* gA0 = A + (size_t)(brow + rA) * K + kc8;
    const unsigned short* gA1 = A + (size_t)(brow + 64 + rA) * K + kc8;
    const unsigned short* gB0 = B + (size_t)(bcol + rA) * K + kc8;
    const unsigned short* gB1 = B + (size_t)(bcol + 64 + rA) * K + kc8;
    unsigned short* lA0 = As + wid * 512;
    unsigned short* lA1 = As + 2048 + wid * 512;
    unsigned short* lB0 = Bs + wid * 512;
    unsigned short* lB1 = Bs + 2048 + wid * 512;

    for (int k0 = 0; k0 < K; k0 += BK) {
        gload_lds16(gA0 + k0, lA0);
        gload_lds16(gA1 + k0, lA1);
        gload_lds16(gB0 + k0, lB0);
        gload_lds16(gB1 + k0, lB1);
        __syncthreads();

        short8 a[4], b[4];
#pragma unroll
        for (int m = 0; m < 4; ++m)
            a[m] = *reinterpret_cast<const short8*>(&As[(wr * 64 + m * 16 + lm) * BK + lg * 8]);
#pragma unroll
        for (int n = 0; n < 4; ++n)
            b[n] = *reinterpret_cast<const short8*>(&Bs[(wc * 64 + n * 16 + lm) * BK + lg * 8]);
#pragma unroll
        for (int m = 0; m < 4; ++m)
#pragma unroll
            for (int n = 0; n < 4; ++n)
                acc[m][n] = __builtin_amdgcn_mfma_f32_16x16x32_bf16(a[m], b[n], acc[m][n], 0, 0, 0);
        __syncthreads();
    }

#pragma unroll
    for (int m = 0; m < 4; ++m) {
#pragma unroll
        for (int r = 0; r < 4; ++r) {
            const size_t base = (size_t)(brow + wr * 64 + m * 16 + lg * 4 + r) * N + bcol + wc * 64 + lm;
#pragma unroll
            for (int n = 0; n < 4; ++n) {
                if (BF16OUT)
                    ((unsigned short*)Cout)[base + n * 16] = f2b(acc[m][n][r]);
                else
                    ((float*)Cout)[base + n * 16] = acc[m][n][r];
            }
        }
    }
}

// ---------------------------------------------------------------------------
// RoPE cos/sin table: tab[s*32 + i] = {cos,sin}(s * theta^(-2i/64))
// ---------------------------------------------------------------------------
__global__ __launch_bounds__(256) void rope_tables(float* __restrict__ tab) {
    int idx = blockIdx.x * blockDim.x + threadIdx.x;   // SEQ*32 total
    int s = idx >> 5, i = idx & 31;
    float inv = powf(10000.0f, -2.0f * (float)i / (float)DH);
    float ang = (float)s * inv;
    tab[idx * 2]     = cosf(ang);
    tab[idx * 2 + 1] = sinf(ang);
}

// ---------------------------------------------------------------------------
// RoPE in place on bf16 q,k via table. q additionally scaled by log2(e)/sqrt(DH).
// ---------------------------------------------------------------------------
__global__ __launch_bounds__(256) void rope_qk_bf16(unsigned short* __restrict__ q,
                                                    unsigned short* __restrict__ k,
                                                    const float* __restrict__ tab,
                                                    int total) {
    int idx = blockIdx.x * blockDim.x + threadIdx.x;
    if (idx >= total) return;
    int i = idx & 31;
    int s = (idx >> 9) & (SEQ - 1);
    float2 cs = reinterpret_cast<const float2*>(tab)[s * 32 + i];
    float c = cs.x, sn = cs.y;
    size_t off = ((size_t)(idx >> 5)) * 64 + 2 * i;
    const float scale = 0.125f * 1.4426950408889634f;   // 1/sqrt(64) * log2(e)
    float qe = b2f(q[off]), qo = b2f(q[off + 1]);
    q[off]     = f2b((qe * c - qo * sn) * scale);
    q[off + 1] = f2b((qe * sn + qo * c) * scale);
    float ke = b2f(k[off]), ko = b2f(k[off + 1]);
    k[off]     = f2b(ke * c - ko * sn);
    k[off + 1] = f2b(ke * sn + ko * c);
}

// ---------------------------------------------------------------------------
// Transpose V: [b, s, h, d] -> vT[(b*NH+h)*DH + d][s]   (bf16)
// ---------------------------------------------------------------------------
__global__ __launch_bounds__(256) void transpose_v(const unsigned short* __restrict__ v,
                                                   unsigned short* __restrict__ vT) {
    __shared__ unsigned short t[64][68];
    const int s0 = blockIdx.x * 64;
    const int bh = blockIdx.y;
    const int b = bh >> 4, h = bh & 15;
    const int tid = threadIdx.x;
    for (int idx = tid; idx < 1024; idx += 256) {
        int s = idx >> 4;
        int dg = (idx & 15) * 4;
        us4 val = *reinterpret_cast<const us4*>(v + (size_t)(b * SEQ + s0 + s) * DM + h * DH + dg);
        *reinterpret_cast<us4*>(&t[s][dg]) = val;
    }
    __syncthreads();
    for (int idx = tid; idx < 1024; idx += 256) {
        int d = idx >> 4;
        int sg = (idx & 15) * 4;
        us4 val;
        val.x = t[sg + 0][d];
        val.y = t[sg + 1][d];
        val.z = t[sg + 2][d];
        val.w = t[sg + 3][d];
        *reinterpret_cast<us4*>(vT + (size_t)(bh * DH + d) * SEQ + s0 + sg) = val;
    }
}

// ---------------------------------------------------------------------------
// MFMA flash attention v4: swapped QK^T -> in-register softmax.
//   S^T = mfma(K_frag, Q_frag): lane (lm,lg) reg r of subtile st holds
//   S[k = kbase + st*16 + lg*4 + r][q = qbase + lm].
//   Softmax per lane (one q): in-reg max/sum trees + 2 shfl_xor(16,32).
//   P -> PV A-fragment via per-wave LDS relayout:
//     dword idx (q=lm): lm*34 + st*8 + lg'*2 + j  (4x ds_write_b64)
//     PV1 frag: dwords lm*34 + (lg>>1)*8 + (lg&1)*4 + {0..3}; PV2: +16.
// Equal-work pairing: wave handles tile (127-p) then tile p (~33 iters each).
// XCD swizzle: bh & 7 == blockIdx.x & 7 (4 bh per XCD, K/V L2-resident).
// ---------------------------------------------------------------------------
#define LOADK(kbase, dst)                                                              \
    {                                                                                  \
        _Pragma("unroll")                                                              \
        for (int st = 0; st < 4; ++st) {                                               \
            const unsigned short* kr = kb + (size_t)((kbase) + st * 16 + lm) * DM;     \
            dst[st * 2]     = *reinterpret_cast<const short8*>(kr + lg * 8);           \
            dst[st * 2 + 1] = *reinterpret_cast<const short8*>(kr + 32 + lg * 8);      \
        }                                                                              \
    }

__global__ __launch_bounds__(256, 3) void attn_mfma(const unsigned short* __restrict__ qbf,
                                                    const unsigned short* __restrict__ kbf,
                                                    const unsigned short* __restrict__ vT,
                                                    unsigned short* __restrict__ o) {
    const int tid  = threadIdx.x;
    const int wid  = tid >> 6;
    const int lane = tid & 63;
    const int lm = lane & 15, lg = lane >> 4;

    const int bid  = blockIdx.x;            // [0,512)
    const int u    = bid >> 3;              // [0,64)
    const int bh   = (bid & 7) + 8 * (u >> 4);
    const int blk4 = u & 15;
    const int p    = blk4 * 4 + wid;        // pair index [0,64)
    const int b = bh >> 4, h = bh & 15;

    __shared__ unsigned int Pex[4][16 * 34];   // per-wave P exchange (8.5 KB)
    unsigned int* PW = Pex[wid];

    const unsigned short* kb = kbf + ((size_t)b * SEQ) * DM + h * DH;
    const unsigned short* vb = vT + ((size_t)bh) * DH * SEQ;

    const int wr_base = lm * 34 + lg * 2;                       // + st*8
    const int rd1 = lm * 34 + (lg >> 1) * 8 + (lg & 1) * 4;     // PV1 dwords
    const int rd2 = rd1 + 16;                                    // PV2 (st+2)

    for (int half = 0; half < 2; ++half) {
        const int qbase = (half == 0 ? (127 - p) : p) * 16;

        const unsigned short* qrow = qbf + ((size_t)(b * SEQ + qbase + lm)) * DM + h * DH;
        short8 qa0 = *reinterpret_cast<const short8*>(qrow + lg * 8);
        short8 qa1 = *reinterpret_cast<const short8*>(qrow + 32 + lg * 8);

        f32x4 o0 = {0.f, 0.f, 0.f, 0.f}, o1 = o0, o2 = o0, o3 = o0;
        float mrun = -INFINITY, lrun = 0.f;

        const int nb = (qbase + 79) >> 6;
        short8 kc[8];
        LOADK(0, kc);

        for (int blk = 0; blk < nb; ++blk) {
            const int kbase = blk << 6;

            // V loads issued early (consumed at PV, hidden under QK+softmax)
            short8 vv[8];
#pragma unroll
            for (int c = 0; c < 4; ++c) {
                const unsigned short* vr = vb + (size_t)(c * 16 + lm) * SEQ + kbase;
                vv[c * 2]     = *reinterpret_cast<const short8*>(vr + lg * 8);
                vv[c * 2 + 1] = *reinterpret_cast<const short8*>(vr + 32 + lg * 8);
            }

            // QK^T swapped: S^T[k][q]
            float s[16];
#pragma unroll
            for (int st = 0; st < 4; ++st) {
                f32x4 t = {0.f, 0.f, 0.f, 0.f};
                t = __builtin_amdgcn_mfma_f32_16x16x32_bf16(kc[st * 2],     qa0, t, 0, 0, 0);
                t = __builtin_amdgcn_mfma_f32_16x16x32_bf16(kc[st * 2 + 1], qa1, t, 0, 0, 0);
#pragma unroll
                for (int r = 0; r < 4; ++r) s[st * 4 + r] = t[r];
            }

            // prefetch next K (consumed next iteration)
            if (blk + 1 < nb) LOADK((blk + 1) << 6, kc);

            // causal mask (last block only crosses the diagonal)
            if (blk == nb - 1) {
#pragma unroll
                for (int st = 0; st < 4; ++st)
#pragma unroll
                    for (int r = 0; r < 4; ++r) {
                        int kk = kbase + st * 16 + lg * 4 + r;
                        s[st * 4 + r] = (kk <= qbase + lm) ? s[st * 4 + r] : -INFINITY;
                    }
            }

            // in-register softmax for q = qbase + lm (exp2 domain)
            float t0 = fmaxf(s[0], s[1]),  t1 = fmaxf(s[2], s[3]);
            float t2 = fmaxf(s[4], s[5]),  t3 = fmaxf(s[6], s[7]);
            float t4 = fmaxf(s[8], s[9]),  t5 = fmaxf(s[10], s[11]);
            float t6 = fmaxf(s[12], s[13]), t7 = fmaxf(s[14], s[15]);
            float mx = fmaxf(fmaxf(fmaxf(t0, t1), fmaxf(t2, t3)),
                             fmaxf(fmaxf(t4, t5), fmaxf(t6, t7)));
            mx = fmaxf(mx, __shfl_xor(mx, 16));
            mx = fmaxf(mx, __shfl_xor(mx, 32));
            float mn  = fmaxf(mrun, mx);
            float fsc = exp2f(mrun - mn);
            mrun = mn;
#pragma unroll
            for (int i = 0; i < 16; ++i) s[i] = exp2f(s[i] - mn);
            float a0 = (s[0] + s[1]) + (s[2] + s[3]);
            float a1 = (s[4] + s[5]) + (s[6] + s[7]);
            float a2 = (s[8] + s[9]) + (s[10] + s[11]);
            float a3 = (s[12] + s[13]) + (s[14] + s[15]);
            float ps = (a0 + a1) + (a2 + a3);
            ps += __shfl_xor(ps, 16);
            ps += __shfl_xor(ps, 32);
            lrun = lrun * fsc + ps;

            // rescale O (output rows q = lg*4 + r live on different lanes)
            float fr[4];
#pragma unroll
            for (int r = 0; r < 4; ++r) fr[r] = __shfl(fsc, lg * 4 + r);
#pragma unroll
            for (int r = 0; r < 4; ++r) {
                o0[r] *= fr[r]; o1[r] *= fr[r]; o2[r] *= fr[r]; o3[r] *= fr[r];
            }

            // pack P (round-to-nearest bf16) and relayout through LDS
#pragma unroll
            for (int st = 0; st < 4; ++st) {
                union { float f; unsigned int u; } e0, e1, e2, e3;
                e0.f = s[st * 4 + 0]; e1.f = s[st * 4 + 1];
                e2.f = s[st * 4 + 2]; e3.f = s[st * 4 + 3];
                u32x2 w;
                w.x = ((e0.u + 0x8000u) >> 16) | ((e1.u + 0x8000u) & 0xFFFF0000u);
                w.y = ((e2.u + 0x8000u) >> 16) | ((e3.u + 0x8000u) & 0xFFFF0000u);
                *reinterpret_cast<u32x2*>(&PW[wr_base + st * 8]) = w;
            }
            __builtin_amdgcn_wave_barrier();
            asm volatile("" ::: "memory");

            union { unsigned int u[4]; short8 v; } pk1, pk2;
            {
                u32x2 x0 = *reinterpret_cast<const u32x2*>(&PW[rd1]);
                u32x2 x1 = *reinterpret_cast<const u32x2*>(&PW[rd1 + 2]);
                pk1.u[0] = x0.x; pk1.u[1] = x0.y; pk1.u[2] = x1.x; pk1.u[3] = x1.y;
                u32x2 y0 = *reinterpret_cast<const u32x2*>(&PW[rd2]);
                u32x2 y1 = *reinterpret_cast<const u32x2*>(&PW[rd2 + 2]);
                pk2.u[0] = y0.x; pk2.u[1] = y0.y; pk2.u[2] = y1.x; pk2.u[3] = y1.y;
            }
            __builtin_amdgcn_wave_barrier();
            asm volatile("" ::: "memory");

            // PV: O[q = lg*4+r][d = lm + 16c]
            o0 = __builtin_amdgcn_mfma_f32_16x16x32_bf16(pk1.v, vv[0], o0, 0, 0, 0);
            o0 = __builtin_amdgcn_mfma_f32_16x16x32_bf16(pk2.v, vv[1], o0, 0, 0, 0);
            o1 = __builtin_amdgcn_mfma_f32_16x16x32_bf16(pk1.v, vv[2], o1, 0, 0, 0);
            o1 = __builtin_amdgcn_mfma_f32_16x16x32_bf16(pk2.v, vv[3], o1, 0, 0, 0);
            o2 = __builtin_amdgcn_mfma_f32_16x16x32_bf16(pk1.v, vv[4], o2, 0, 0, 0);
            o2 = __builtin_amdgcn_mfma_f32_16x16x32_bf16(pk2.v, vv[5], o2, 0, 0, 0);
            o3 = __builtin_amdgcn_mfma_f32_16x16x32_bf16(pk1.v, vv[6], o3, 0, 0, 0);
            o3 = __builtin_amdgcn_mfma_f32_16x16x32_bf16(pk2.v, vv[7], o3, 0, 0, 0);
        }

        // epilogue: fetch l for output rows, normalize, store bf16
        float linv[4];
#pragma unroll
        for (int r = 0; r < 4; ++r) linv[r] = 1.0f / __shfl(lrun, lg * 4 + r);
#pragma unroll
        for (int r = 0; r < 4; ++r) {
            const size_t rowoff = ((size_t)(b * SEQ + qbase + lg * 4 + r)) * DM + h * DH;
            o[rowoff + 0 * 16 + lm] = f2b(o0[r] * linv[r]);
            o[rowoff + 1 * 16 + lm] = f2b(o1[r] * linv[r]);
            o[rowoff + 2 * 16 + lm] = f2b(o2[r] * linv[r]);
            o[rowoff + 3 * 16 + lm] = f2b(o3[r] * linv[r]);
        }
    }
}

// ---------------------------------------------------------------------------
extern "C" void kernel_launch(void* const* d_in, const int* in_sizes, int n_in,
                              void* d_out, int out_size, void* d_ws, size_t ws_size,
                              hipStream_t stream) {
    const float* x  = (const float*)d_in[0];
    const float* wq = (const float*)d_in[1];
    const float* wk = (const float*)d_in[2];
    const float* wv = (const float*)d_in[3];
    const float* wo = (const float*)d_in[4];
    float* out = (float*)d_out;

    const int TSZ = MROWS * DM;      // 4M
    const int WSZ = DM * DM;         // 1M
    char* ws = (char*)d_ws;
    const size_t MB = 1024 * 1024;
    unsigned short* xb      = (unsigned short*)(ws);             // 8 MB
    unsigned short* wqb     = (unsigned short*)(ws + 8 * MB);    // 2 MB each
    unsigned short* wkb     = (unsigned short*)(ws + 10 * MB);
    unsigned short* wvb     = (unsigned short*)(ws + 12 * MB);
    unsigned short* wob     = (unsigned short*)(ws + 14 * MB);
    unsigned short* qbf     = (unsigned short*)(ws + 16 * MB);   // 8 MB
    unsigned short* kbf     = (unsigned short*)(ws + 24 * MB);   // 8 MB
    unsigned short* vtmp    = (unsigned short*)(ws + 32 * MB);   // 8 MB
    unsigned short* vT      = (unsigned short*)(ws + 40 * MB);   // 8 MB
    unsigned short* attn_bf = (unsigned short*)(ws + 32 * MB);   // reuse vtmp after transpose
    float*          ropetab = (float*)(ws + 40 * MB);            // reuse vT region pre-transpose

    cvt_f32_bf16<<<TSZ / 4 / 256, 256, 0, stream>>>(x, xb, TSZ);
    cvt_f32_bf16<<<WSZ / 4 / 256, 256, 0, stream>>>(wq, wqb, WSZ);
    cvt_f32_bf16<<<WSZ / 4 / 256, 256, 0, stream>>>(wk, wkb, WSZ);
    cvt_f32_bf16<<<WSZ / 4 / 256, 256, 0, stream>>>(wv, wvb, WSZ);
    cvt_f32_bf16<<<WSZ / 4 / 256, 256, 0, stream>>>(wo, wob, WSZ);

    dim3 grd(DM / BN, MROWS / BM);   // (8, 32)
    gemm_bt_mfma<true><<<grd, 256, 0, stream>>>(xb, wqb, qbf,  MROWS, DM, DM);
    gemm_bt_mfma<true><<<grd, 256, 0, stream>>>(xb, wkb, kbf,  MROWS, DM, DM);
    gemm_bt_mfma<true><<<grd, 256, 0, stream>>>(xb, wvb, vtmp, MROWS, DM, DM);

    rope_tables<<<SEQ * 32 / 256, 256, 0, stream>>>(ropetab);
    int total = MROWS * NH * 32;
    rope_qk_bf16<<<(total + 255) / 256, 256, 0, stream>>>(qbf, kbf, ropetab, total);

    transpose_v<<<dim3(SEQ / 64, B_SZ * NH), 256, 0, stream>>>(vtmp, vT);

    attn_mfma<<<512, 256, 0, stream>>>(qbf, kbf, vT, attn_bf);

    gemm_bt_mfma<false><<<grd, 256, 0, stream>>>(attn_bf, wob, out, MROWS, DM, DM);
}

// Round 7
// 227.044 us; speedup vs baseline: 29.4629x; 1.1765x over previous
//
#include <hip/hip_runtime.h>
#include <math.h>

// Problem constants
#define B_SZ   2
#define SEQ    2048
#define DM     1024
#define NH     16
#define DH     64
#define MROWS  (B_SZ * SEQ)      // 4096
#define DQKV   (3 * DM)          // 3072, interleaved qkv row stride

typedef __attribute__((ext_vector_type(8))) short short8;
typedef __attribute__((ext_vector_type(4))) float f32x4;
typedef __attribute__((ext_vector_type(4))) unsigned short us4;
typedef __attribute__((ext_vector_type(2))) unsigned int u32x2;

__device__ __forceinline__ float b2f(unsigned short u) {
    union { float f; unsigned int i; } x; x.i = ((unsigned int)u) << 16; return x.f;
}
__device__ __forceinline__ unsigned short f2b(float f) {
    union { float f; unsigned int i; } x; x.f = f;
    return (unsigned short)((x.i + 0x7fffu + ((x.i >> 16) & 1u)) >> 16);
}

// async global->LDS, 16B per lane; lds base must be wave-uniform (HW adds lane*16)
__device__ __forceinline__ void gload_lds16(const unsigned short* g, unsigned short* lds_base_uniform) {
    __builtin_amdgcn_global_load_lds(
        (const __attribute__((address_space(1))) unsigned int*)g,
        (__attribute__((address_space(3))) unsigned int*)lds_base_uniform,
        16, 0, 0);
}

// ---------------------------------------------------------------------------
// f32 -> bf16 conversion (vectorized, n % 4 == 0)
// ---------------------------------------------------------------------------
__global__ __launch_bounds__(256) void cvt_f32_bf16(const float* __restrict__ in,
                                                    unsigned short* __restrict__ out, int n) {
    int i = blockIdx.x * blockDim.x + threadIdx.x;
    if (i * 4 >= n) return;
    float4 v = reinterpret_cast<const float4*>(in)[i];
    us4 o = { f2b(v.x), f2b(v.y), f2b(v.z), f2b(v.w) };
    reinterpret_cast<us4*>(out)[i] = o;
}

// 3 weights -> one concatenated bf16 buffer [3*DM][DM]
__global__ __launch_bounds__(256) void cvt3_f32_bf16(const float* __restrict__ a,
                                                     const float* __restrict__ b,
                                                     const float* __restrict__ c,
                                                     unsigned short* __restrict__ out) {
    const int each4 = DM * DM / 4;               // vec4 count per weight
    int i = blockIdx.x * blockDim.x + threadIdx.x;   // [0, 3*each4)
    const float* src = (i < each4) ? a : (i < 2 * each4) ? b : c;
    int off = (i < each4) ? i : (i < 2 * each4) ? i - each4 : i - 2 * each4;
    float4 v = reinterpret_cast<const float4*>(src)[off];
    us4 o = { f2b(v.x), f2b(v.y), f2b(v.z), f2b(v.w) };
    reinterpret_cast<us4*>(out)[i] = o;
}

// ---------------------------------------------------------------------------
// bf16 MFMA GEMM (m97 structure, single-buffered), 128x128 tile, BK=32.
// ---------------------------------------------------------------------------
#define BM 128
#define BN 128
#define BK 32

template <bool BF16OUT>
__global__ __launch_bounds__(256) void gemm_bt_mfma(const unsigned short* __restrict__ A,
                                                    const unsigned short* __restrict__ B,
                                                    void* __restrict__ Cout,
                                                    int M, int N, int K) {
    __shared__ unsigned short As[BM * BK];   // 8 KB
    __shared__ unsigned short Bs[BN * BK];   // 8 KB
    const int tid  = threadIdx.x;
    const int lane = tid & 63, wid = tid >> 6;
    const int wr = wid >> 1, wc = wid & 1;
    const int lm = lane & 15, lg = lane >> 4;
    const int brow = blockIdx.y * BM, bcol = blockIdx.x * BN;

    f32x4 acc[4][4] = {};

    const int rA  = tid >> 2;
    const int kc8 = (tid & 3) * 8;
    const unsigned short* gA0 = A + (size_t)(brow + rA) * K + kc8;
    const unsigned short* gA1 = A + (size_t)(brow + 64 + rA) * K + kc8;
    const unsigned short* gB0 = B + (size_t)(bcol + rA) * K + kc8;
    const unsigned short* gB1 = B + (size_t)(bcol + 64 + rA) * K + kc8;
    unsigned short* lA0 = As + wid * 512;
    unsigned short* lA1 = As + 2048 + wid * 512;
    unsigned short* lB0 = Bs + wid * 512;
    unsigned short* lB1 = Bs + 2048 + wid * 512;

    for (int k0 = 0; k0 < K; k0 += BK) {
        gload_lds16(gA0 + k0, lA0);
        gload_lds16(gA1 + k0, lA1);
        gload_lds16(gB0 + k0, lB0);
        gload_lds16(gB1 + k0, lB1);
        __syncthreads();

        short8 a[4], b[4];
#pragma unroll
        for (int m = 0; m < 4; ++m)
            a[m] = *reinterpret_cast<const short8*>(&As[(wr * 64 + m * 16 + lm) * BK + lg * 8]);
#pragma unroll
        for (int n = 0; n < 4; ++n)
            b[n] = *reinterpret_cast<const short8*>(&Bs[(wc * 64 + n * 16 + lm) * BK + lg * 8]);
#pragma unroll
        for (int m = 0; m < 4; ++m)
#pragma unroll
            for (int n = 0; n < 4; ++n)
                acc[m][n] = __builtin_amdgcn_mfma_f32_16x16x32_bf16(a[m], b[n], acc[m][n], 0, 0, 0);
        __syncthreads();
    }

#pragma unroll
    for (int m = 0; m < 4; ++m) {
#pragma unroll
        for (int r = 0; r < 4; ++r) {
            const size_t base = (size_t)(brow + wr * 64 + m * 16 + lg * 4 + r) * N + bcol + wc * 64 + lm;
#pragma unroll
            for (int n = 0; n < 4; ++n) {
                if (BF16OUT)
                    ((unsigned short*)Cout)[base + n * 16] = f2b(acc[m][n][r]);
                else
                    ((float*)Cout)[base + n * 16] = acc[m][n][r];
            }
        }
    }
}

// ---------------------------------------------------------------------------
// RoPE in place on interleaved qkv (q at col 0.., k at col 1024..).
// One s per block; 32 cos/sin computed into LDS. q scaled by log2(e)/8.
// ---------------------------------------------------------------------------
__global__ __launch_bounds__(256) void rope_qk_bf16(unsigned short* __restrict__ qkv) {
    __shared__ float cs_c[32], cs_s[32];
    const int tid = threadIdx.x;
    const int row = blockIdx.x >> 1;              // [0, MROWS)
    const int s   = row & (SEQ - 1);
    if (tid < 32) {
        float inv = powf(10000.0f, -(float)tid / 32.0f);
        float ang = (float)s * inv;
        cs_c[tid] = cosf(ang);
        cs_s[tid] = sinf(ang);
    }
    __syncthreads();
    const int idx = blockIdx.x * 256 + tid;
    const int i = idx & 31;
    const int h = (idx >> 5) & 15;
    const float c = cs_c[i], sn = cs_s[i];
    const size_t off = (size_t)row * DQKV + h * 64 + 2 * i;
    const float scale = 0.125f * 1.4426950408889634f;   // 1/sqrt(64) * log2(e)
    float qe = b2f(qkv[off]), qo = b2f(qkv[off + 1]);
    qkv[off]     = f2b((qe * c - qo * sn) * scale);
    qkv[off + 1] = f2b((qe * sn + qo * c) * scale);
    float ke = b2f(qkv[off + DM]), ko = b2f(qkv[off + DM + 1]);
    qkv[off + DM]     = f2b(ke * c - ko * sn);
    qkv[off + DM + 1] = f2b(ke * sn + ko * c);
}

// ---------------------------------------------------------------------------
// Transpose V (qkv cols 2048..3071): -> vT[(b*NH+h)*DH + d][s]   (bf16)
// ---------------------------------------------------------------------------
__global__ __launch_bounds__(256) void transpose_v(const unsigned short* __restrict__ qkv,
                                                   unsigned short* __restrict__ vT) {
    __shared__ unsigned short t[64][68];
    const int s0 = blockIdx.x * 64;
    const int bh = blockIdx.y;
    const int b = bh >> 4, h = bh & 15;
    const int tid = threadIdx.x;
    for (int idx = tid; idx < 1024; idx += 256) {
        int s = idx >> 4;
        int dg = (idx & 15) * 4;
        us4 val = *reinterpret_cast<const us4*>(qkv + (size_t)(b * SEQ + s0 + s) * DQKV + 2 * DM + h * DH + dg);
        *reinterpret_cast<us4*>(&t[s][dg]) = val;
    }
    __syncthreads();
    for (int idx = tid; idx < 1024; idx += 256) {
        int d = idx >> 4;
        int sg = (idx & 15) * 4;
        us4 val;
        val.x = t[sg + 0][d];
        val.y = t[sg + 1][d];
        val.z = t[sg + 2][d];
        val.w = t[sg + 3][d];
        *reinterpret_cast<us4*>(vT + (size_t)(bh * DH + d) * SEQ + s0 + sg) = val;
    }
}

// ---------------------------------------------------------------------------
// MFMA flash attention v5: swapped QK^T + in-register softmax (round 6),
// now ONE 16-row q-tile per wave -> 1024 blocks, all resident (4 blk/CU,
// 4 waves/SIMD). Per-block tile set {j,127-j,63-j,64+j} = equal work;
// rotated by j across waves to balance SIMDs. XCD swizzle: 4 bh per XCD.
// qkv interleaved (row stride 3072): q at col 0, k at col 1024.
// ---------------------------------------------------------------------------
#define LOADK(kbase, dst)                                                              \
    {                                                                                  \
        _Pragma("unroll")                                                              \
        for (int st = 0; st < 4; ++st) {                                               \
            const unsigned short* kr = kb + (size_t)((kbase) + st * 16 + lm) * DQKV;   \
            dst[st * 2]     = *reinterpret_cast<const short8*>(kr + lg * 8);           \
            dst[st * 2 + 1] = *reinterpret_cast<const short8*>(kr + 32 + lg * 8);      \
        }                                                                              \
    }

__global__ __launch_bounds__(256, 4) void attn_mfma(const unsigned short* __restrict__ qkv,
                                                    const unsigned short* __restrict__ vT,
                                                    unsigned short* __restrict__ o) {
    const int tid  = threadIdx.x;
    const int wid  = tid >> 6;
    const int lane = tid & 63;
    const int lm = lane & 15, lg = lane >> 4;

    const int bid = blockIdx.x;             // [0,1024)
    const int u   = bid >> 3;               // [0,128)
    const int bh  = (bid & 7) + 8 * (u >> 5);
    const int j   = u & 31;
    const int sel = (wid + j) & 3;
    const int p   = (sel == 0) ? j : (sel == 1) ? 127 - j : (sel == 2) ? 63 - j : 64 + j;
    const int b = bh >> 4, h = bh & 15;
    const int qbase = p * 16;

    __shared__ unsigned int Pex[4][16 * 34];   // per-wave P exchange (8.5 KB)
    unsigned int* PW = Pex[wid];

    const unsigned short* kb = qkv + ((size_t)b * SEQ) * DQKV + DM + h * DH;
    const unsigned short* vb = vT + ((size_t)bh) * DH * SEQ;

    const int wr_base = lm * 34 + lg * 2;                       // + st*8
    const int rd1 = lm * 34 + (lg >> 1) * 8 + (lg & 1) * 4;     // PV1 dwords
    const int rd2 = rd1 + 16;                                    // PV2 (st+2)

    const unsigned short* qrow = qkv + ((size_t)(b * SEQ + qbase + lm)) * DQKV + h * DH;
    short8 qa0 = *reinterpret_cast<const short8*>(qrow + lg * 8);
    short8 qa1 = *reinterpret_cast<const short8*>(qrow + 32 + lg * 8);

    f32x4 o0 = {0.f, 0.f, 0.f, 0.f}, o1 = o0, o2 = o0, o3 = o0;
    float mrun = -INFINITY, lrun = 0.f;

    const int nb = (qbase + 79) >> 6;
    short8 kc[8];
    LOADK(0, kc);

    for (int blk = 0; blk < nb; ++blk) {
        const int kbase = blk << 6;

        // V loads issued early (consumed at PV, hidden under QK+softmax)
        short8 vv[8];
#pragma unroll
        for (int c = 0; c < 4; ++c) {
            const unsigned short* vr = vb + (size_t)(c * 16 + lm) * SEQ + kbase;
            vv[c * 2]     = *reinterpret_cast<const short8*>(vr + lg * 8);
            vv[c * 2 + 1] = *reinterpret_cast<const short8*>(vr + 32 + lg * 8);
        }

        // QK^T swapped: S^T[k][q]
        float s[16];
#pragma unroll
        for (int st = 0; st < 4; ++st) {
            f32x4 t = {0.f, 0.f, 0.f, 0.f};
            t = __builtin_amdgcn_mfma_f32_16x16x32_bf16(kc[st * 2],     qa0, t, 0, 0, 0);
            t = __builtin_amdgcn_mfma_f32_16x16x32_bf16(kc[st * 2 + 1], qa1, t, 0, 0, 0);
#pragma unroll
            for (int r = 0; r < 4; ++r) s[st * 4 + r] = t[r];
        }

        // prefetch next K (consumed next iteration)
        if (blk + 1 < nb) LOADK((blk + 1) << 6, kc);

        // causal mask (last block only crosses the diagonal)
        if (blk == nb - 1) {
#pragma unroll
            for (int st = 0; st < 4; ++st)
#pragma unroll
                for (int r = 0; r < 4; ++r) {
                    int kk = kbase + st * 16 + lg * 4 + r;
                    s[st * 4 + r] = (kk <= qbase + lm) ? s[st * 4 + r] : -INFINITY;
                }
        }

        // in-register softmax for q = qbase + lm (exp2 domain)
        float t0 = fmaxf(s[0], s[1]),  t1 = fmaxf(s[2], s[3]);
        float t2 = fmaxf(s[4], s[5]),  t3 = fmaxf(s[6], s[7]);
        float t4 = fmaxf(s[8], s[9]),  t5 = fmaxf(s[10], s[11]);
        float t6 = fmaxf(s[12], s[13]), t7 = fmaxf(s[14], s[15]);
        float mx = fmaxf(fmaxf(fmaxf(t0, t1), fmaxf(t2, t3)),
                         fmaxf(fmaxf(t4, t5), fmaxf(t6, t7)));
        mx = fmaxf(mx, __shfl_xor(mx, 16));
        mx = fmaxf(mx, __shfl_xor(mx, 32));
        float mn  = fmaxf(mrun, mx);
        float fsc = exp2f(mrun - mn);
        mrun = mn;
#pragma unroll
        for (int i = 0; i < 16; ++i) s[i] = exp2f(s[i] - mn);
        float a0 = (s[0] + s[1]) + (s[2] + s[3]);
        float a1 = (s[4] + s[5]) + (s[6] + s[7]);
        float a2 = (s[8] + s[9]) + (s[10] + s[11]);
        float a3 = (s[12] + s[13]) + (s[14] + s[15]);
        float ps = (a0 + a1) + (a2 + a3);
        ps += __shfl_xor(ps, 16);
        ps += __shfl_xor(ps, 32);
        lrun = lrun * fsc + ps;

        // rescale O (output rows q = lg*4 + r live on different lanes)
        float fr[4];
#pragma unroll
        for (int r = 0; r < 4; ++r) fr[r] = __shfl(fsc, lg * 4 + r);
#pragma unroll
        for (int r = 0; r < 4; ++r) {
            o0[r] *= fr[r]; o1[r] *= fr[r]; o2[r] *= fr[r]; o3[r] *= fr[r];
        }

        // pack P (round-to-nearest bf16) and relayout through LDS
#pragma unroll
        for (int st = 0; st < 4; ++st) {
            union { float f; unsigned int u; } e0, e1, e2, e3;
            e0.f = s[st * 4 + 0]; e1.f = s[st * 4 + 1];
            e2.f = s[st * 4 + 2]; e3.f = s[st * 4 + 3];
            u32x2 w;
            w.x = ((e0.u + 0x8000u) >> 16) | ((e1.u + 0x8000u) & 0xFFFF0000u);
            w.y = ((e2.u + 0x8000u) >> 16) | ((e3.u + 0x8000u) & 0xFFFF0000u);
            *reinterpret_cast<u32x2*>(&PW[wr_base + st * 8]) = w;
        }
        __builtin_amdgcn_wave_barrier();
        asm volatile("" ::: "memory");

        union { unsigned int u[4]; short8 v; } pk1, pk2;
        {
            u32x2 x0 = *reinterpret_cast<const u32x2*>(&PW[rd1]);
            u32x2 x1 = *reinterpret_cast<const u32x2*>(&PW[rd1 + 2]);
            pk1.u[0] = x0.x; pk1.u[1] = x0.y; pk1.u[2] = x1.x; pk1.u[3] = x1.y;
            u32x2 y0 = *reinterpret_cast<const u32x2*>(&PW[rd2]);
            u32x2 y1 = *reinterpret_cast<const u32x2*>(&PW[rd2 + 2]);
            pk2.u[0] = y0.x; pk2.u[1] = y0.y; pk2.u[2] = y1.x; pk2.u[3] = y1.y;
        }
        __builtin_amdgcn_wave_barrier();
        asm volatile("" ::: "memory");

        // PV: O[q = lg*4+r][d = lm + 16c]
        o0 = __builtin_amdgcn_mfma_f32_16x16x32_bf16(pk1.v, vv[0], o0, 0, 0, 0);
        o0 = __builtin_amdgcn_mfma_f32_16x16x32_bf16(pk2.v, vv[1], o0, 0, 0, 0);
        o1 = __builtin_amdgcn_mfma_f32_16x16x32_bf16(pk1.v, vv[2], o1, 0, 0, 0);
        o1 = __builtin_amdgcn_mfma_f32_16x16x32_bf16(pk2.v, vv[3], o1, 0, 0, 0);
        o2 = __builtin_amdgcn_mfma_f32_16x16x32_bf16(pk1.v, vv[4], o2, 0, 0, 0);
        o2 = __builtin_amdgcn_mfma_f32_16x16x32_bf16(pk2.v, vv[5], o2, 0, 0, 0);
        o3 = __builtin_amdgcn_mfma_f32_16x16x32_bf16(pk1.v, vv[6], o3, 0, 0, 0);
        o3 = __builtin_amdgcn_mfma_f32_16x16x32_bf16(pk2.v, vv[7], o3, 0, 0, 0);
    }

    // epilogue: fetch l for output rows, normalize, store bf16
    float linv[4];
#pragma unroll
    for (int r = 0; r < 4; ++r) linv[r] = 1.0f / __shfl(lrun, lg * 4 + r);
#pragma unroll
    for (int r = 0; r < 4; ++r) {
        const size_t rowoff = ((size_t)(b * SEQ + qbase + lg * 4 + r)) * DM + h * DH;
        o[rowoff + 0 * 16 + lm] = f2b(o0[r] * linv[r]);
        o[rowoff + 1 * 16 + lm] = f2b(o1[r] * linv[r]);
        o[rowoff + 2 * 16 + lm] = f2b(o2[r] * linv[r]);
        o[rowoff + 3 * 16 + lm] = f2b(o3[r] * linv[r]);
    }
}

// ---------------------------------------------------------------------------
extern "C" void kernel_launch(void* const* d_in, const int* in_sizes, int n_in,
                              void* d_out, int out_size, void* d_ws, size_t ws_size,
                              hipStream_t stream) {
    const float* x  = (const float*)d_in[0];
    const float* wq = (const float*)d_in[1];
    const float* wk = (const float*)d_in[2];
    const float* wv = (const float*)d_in[3];
    const float* wo = (const float*)d_in[4];
    float* out = (float*)d_out;

    const int TSZ = MROWS * DM;      // 4M
    const int WSZ = DM * DM;         // 1M
    char* ws = (char*)d_ws;
    const size_t MB = 1024 * 1024;
    unsigned short* xb      = (unsigned short*)(ws);             // 8 MB  (reused for attn_bf)
    unsigned short* wqkv    = (unsigned short*)(ws + 8 * MB);    // 6 MB
    unsigned short* wob     = (unsigned short*)(ws + 14 * MB);   // 2 MB
    unsigned short* qkv     = (unsigned short*)(ws + 16 * MB);   // 24 MB (interleaved q|k|v)
    unsigned short* vT      = (unsigned short*)(ws + 40 * MB);   // 8 MB
    unsigned short* attn_bf = xb;                                // xb dead after QKV GEMM

    cvt_f32_bf16<<<TSZ / 4 / 256, 256, 0, stream>>>(x, xb, TSZ);
    cvt3_f32_bf16<<<3 * WSZ / 4 / 256, 256, 0, stream>>>(wq, wk, wv, wqkv);
    cvt_f32_bf16<<<WSZ / 4 / 256, 256, 0, stream>>>(wo, wob, WSZ);

    // fused QKV GEMM: (4096 x 1024) x (3072 x 1024)^T -> qkv interleaved
    gemm_bt_mfma<true><<<dim3(DQKV / BN, MROWS / BM), 256, 0, stream>>>(xb, wqkv, qkv, MROWS, DQKV, DM);

    rope_qk_bf16<<<MROWS * 2, 256, 0, stream>>>(qkv);

    transpose_v<<<dim3(SEQ / 64, B_SZ * NH), 256, 0, stream>>>(qkv, vT);

    attn_mfma<<<1024, 256, 0, stream>>>(qkv, vT, attn_bf);

    gemm_bt_mfma<false><<<dim3(DM / BN, MROWS / BM), 256, 0, stream>>>(attn_bf, wob, out, MROWS, DM, DM);
}